// Round 3
// baseline (735.886 us; speedup 1.0000x reference)
//
#include <hip/hip_runtime.h>
#include <hip/hip_bf16.h>

// Problem constants
#define BB 8
#define NN 16384
#define MM 4096
#define C1 64
#define C2 256
#define K1 320            // C1 + C2
#define CO 256
#define MTOT (BB * NN)    // 131072

// Workspace layout (bytes)
#define STATS_OFF 0                 // 8*256 floats
#define FLAG_OFF  8192
#define W1B_OFF   16384             // bf16 256x320
#define W2B_OFF   180224            // bf16 256x256
#define F2T_OFF   327680            // bf16 [B,M,C2] = 16777216 B
#define XT_OFF    (327680 + 16777216)              // bf16 [MTOT,320]
#define H2_OFF    (327680 + 16777216 + 83886080)   // bf16 [B,CO,N]

typedef short v8s __attribute__((ext_vector_type(8)));
typedef float v4f __attribute__((ext_vector_type(4)));

__device__ __forceinline__ float bf2f(unsigned short u) {
    unsigned v = ((unsigned)u) << 16;
    float f;
    __builtin_memcpy(&f, &v, 4);
    return f;
}
__device__ __forceinline__ unsigned short f2bf(float f) {
    unsigned u;
    __builtin_memcpy(&u, &f, 4);
    unsigned r = u + 0x7fffu + ((u >> 16) & 1u);  // RNE
    return (unsigned short)(r >> 16);
}

// ---------------- prep: zero stats, idx width flag, W1/W2 -> bf16 ----------
__global__ void k_prep(const void* idx_raw, int* flag64, float* stats,
                       const float* __restrict__ W1, unsigned short* __restrict__ W1b,
                       const float* __restrict__ W2, unsigned short* __restrict__ W2b) {
    int blk = blockIdx.x;
    int t = threadIdx.x;
    if (blk < 320) {
        int e = blk * 256 + t;
        W1b[e] = f2bf(W1[e]);
    } else if (blk < 576) {
        int e = (blk - 320) * 256 + t;
        W2b[e] = f2bf(W2[e]);
    } else {
        for (int i = t; i < 8 * 256; i += 256) stats[i] = 0.f;
        if (t == 0) {
            const int* a = (const int*)idx_raw;
            int all0 = 1;
            for (int j = 1; j < 64; j += 2) all0 &= (a[j] == 0);
            *flag64 = all0;  // 1 => idx int64
        }
    }
}

// ------- transpose f2 [B,C2,M] -> f2t bf16 [B,M,C2]; 64ch x 32m tiles ------
__global__ void k_tr_f2(const float* __restrict__ f2, unsigned short* __restrict__ f2t) {
    __shared__ float tile[64][33];
    int b = blockIdx.z;
    int c0 = blockIdx.y * 64;
    int m0 = blockIdx.x * 32;
    int t = threadIdx.x;
    int lm = t & 31, lc = t >> 5;          // lc 0..7
    const float* src = f2 + ((size_t)b * C2 + c0) * MM + m0;
#pragma unroll
    for (int j = 0; j < 8; ++j)
        tile[lc + 8 * j][lm] = src[(size_t)(lc + 8 * j) * MM + lm];
    __syncthreads();
    int m = t >> 3, c8 = (t & 7) * 8;      // m 0..31, c8 0..56
    unsigned short tmp[8];
#pragma unroll
    for (int k = 0; k < 8; ++k) tmp[k] = f2bf(tile[c8 + k][m]);
    uint4 v;
    v.x = (unsigned)tmp[0] | ((unsigned)tmp[1] << 16);
    v.y = (unsigned)tmp[2] | ((unsigned)tmp[3] << 16);
    v.z = (unsigned)tmp[4] | ((unsigned)tmp[5] << 16);
    v.w = (unsigned)tmp[6] | ((unsigned)tmp[7] << 16);
    *(uint4*)&f2t[((size_t)b * MM + m0 + m) * C2 + c0 + c8] = v;
}

// ------- transpose f1 [B,C1,N] -> xT[:,0:64] bf16; 64ch x 32n tiles --------
__global__ void k_tr_f1(const float* __restrict__ f1, unsigned short* __restrict__ xT) {
    __shared__ float tile[64][33];
    int b = blockIdx.z;
    int n0 = blockIdx.x * 32;
    int t = threadIdx.x;
    int lm = t & 31, lc = t >> 5;
    const float* src = f1 + ((size_t)b * C1) * NN + n0;
#pragma unroll
    for (int j = 0; j < 8; ++j)
        tile[lc + 8 * j][lm] = src[(size_t)(lc + 8 * j) * NN + lm];
    __syncthreads();
    int m = t >> 3, c8 = (t & 7) * 8;
    unsigned short tmp[8];
#pragma unroll
    for (int k = 0; k < 8; ++k) tmp[k] = f2bf(tile[c8 + k][m]);
    uint4 v;
    v.x = (unsigned)tmp[0] | ((unsigned)tmp[1] << 16);
    v.y = (unsigned)tmp[2] | ((unsigned)tmp[3] << 16);
    v.z = (unsigned)tmp[4] | ((unsigned)tmp[5] << 16);
    v.w = (unsigned)tmp[6] | ((unsigned)tmp[7] << 16);
    *(uint4*)&xT[((size_t)b * NN + n0 + m) * K1 + c8] = v;
}

// ---------------- 3-NN inverse-distance interpolation -> xT[:,64:320] -------
__global__ void k_interp(const float* __restrict__ p1, const float* __restrict__ p2,
                         const void* __restrict__ idxv, const int* __restrict__ flag64,
                         const unsigned short* __restrict__ f2t,
                         unsigned short* __restrict__ xT) {
    int t = threadIdx.x;
    int p = t >> 5, lane = t & 31;
    size_t pt = (size_t)blockIdx.x * 8 + p;
    int b = (int)(pt >> 14);
    int m0, m1, m2;
    if (*flag64) {
        const long long* id = (const long long*)idxv;
        m0 = (int)id[pt * 3 + 0]; m1 = (int)id[pt * 3 + 1]; m2 = (int)id[pt * 3 + 2];
    } else {
        const int* id = (const int*)idxv;
        m0 = id[pt * 3 + 0]; m1 = id[pt * 3 + 1]; m2 = id[pt * 3 + 2];
    }
    float qx = p1[pt * 3 + 0], qy = p1[pt * 3 + 1], qz = p1[pt * 3 + 2];
    const float* pb = p2 + (size_t)b * MM * 3;
    float dx, dy, dz;
    dx = qx - pb[m0 * 3 + 0]; dy = qy - pb[m0 * 3 + 1]; dz = qz - pb[m0 * 3 + 2];
    float d0 = dx * dx + dy * dy + dz * dz;
    dx = qx - pb[m1 * 3 + 0]; dy = qy - pb[m1 * 3 + 1]; dz = qz - pb[m1 * 3 + 2];
    float d1 = dx * dx + dy * dy + dz * dz;
    dx = qx - pb[m2 * 3 + 0]; dy = qy - pb[m2 * 3 + 1]; dz = qz - pb[m2 * 3 + 2];
    float d2v = dx * dx + dy * dy + dz * dz;
    float r0 = 1.f / (d0 + 1e-8f), r1 = 1.f / (d1 + 1e-8f), r2 = 1.f / (d2v + 1e-8f);
    float inv = 1.f / (r0 + r1 + r2);
    float w0 = r0 * inv, w1 = r1 * inv, w2 = r2 * inv;

    const unsigned short* fb = f2t + (size_t)b * MM * C2;
    int c0 = lane * 8;
    uint4 va = *(const uint4*)(fb + (size_t)m0 * C2 + c0);
    uint4 vb = *(const uint4*)(fb + (size_t)m1 * C2 + c0);
    uint4 vc = *(const uint4*)(fb + (size_t)m2 * C2 + c0);

    float r[8];
    {
        const unsigned av[4] = {va.x, va.y, va.z, va.w};
        const unsigned bv[4] = {vb.x, vb.y, vb.z, vb.w};
        const unsigned cv[4] = {vc.x, vc.y, vc.z, vc.w};
#pragma unroll
        for (int q = 0; q < 4; ++q) {
            r[2 * q + 0] = w0 * bf2f((unsigned short)(av[q] & 0xffff))
                         + w1 * bf2f((unsigned short)(bv[q] & 0xffff))
                         + w2 * bf2f((unsigned short)(cv[q] & 0xffff));
            r[2 * q + 1] = w0 * bf2f((unsigned short)(av[q] >> 16))
                         + w1 * bf2f((unsigned short)(bv[q] >> 16))
                         + w2 * bf2f((unsigned short)(cv[q] >> 16));
        }
    }
    uint4 outv;
    outv.x = (unsigned)f2bf(r[0]) | ((unsigned)f2bf(r[1]) << 16);
    outv.y = (unsigned)f2bf(r[2]) | ((unsigned)f2bf(r[3]) << 16);
    outv.z = (unsigned)f2bf(r[4]) | ((unsigned)f2bf(r[5]) << 16);
    outv.w = (unsigned)f2bf(r[6]) | ((unsigned)f2bf(r[7]) << 16);
    *(uint4*)(xT + pt * K1 + C1 + c0) = outv;
}

// ================= MFMA GEMM1: h1 = xT @ W1^T (bf16), + BN1 stats ==========
// Staging: linear coalesced uint4 reg loads -> ds_write_b128 at XOR-swizzled
// slot (NO global_load_lds: swizzled-source LDS-DMA was the r1/r2 4x poison).
// LDS slot s of row r holds G[r][s ^ (r&7)*8] => conflict-free ds_read_b128.
// A-tile (xT, HBM stream) prefetched one iter ahead in regs; W-tile L2-hot.
// Swapped operands => lane holds 4 consecutive co => direct 8B stores + reg stats.
#define TM 128
#define TN 128
#define TK 64
__launch_bounds__(256)
__global__ void k_gemm1(const unsigned short* __restrict__ xT,
                        const unsigned short* __restrict__ W1b,
                        unsigned short* __restrict__ h1,
                        float* __restrict__ sum1, float* __restrict__ ssq1) {
    __shared__ unsigned short smem[TM * TK + TN * TK];   // Xs | Ws
    unsigned short* Xs = smem;
    unsigned short* Ws = smem + TM * TK;
    const int t = threadIdx.x;
    const int lane = t & 63, w = t >> 6;
    const int cosub = (w >> 1) * 64;   // wave's co sub-block
    const int nsub = (w & 1) * 64;     // wave's n sub-block
    const long rbase = (long)blockIdx.x * TM;   // n base
    const int cb = blockIdx.y * TN;             // co base

    v4f acc[4][4];   // [r=co-tile][c=n-tile]
#pragma unroll
    for (int r = 0; r < 4; ++r)
#pragma unroll
        for (int c = 0; c < 4; ++c) acc[r][c] = (v4f)(0.f);

    const int srow = w * 32 + (lane >> 3);
    const int schl = (lane & 7) * 8;                         // linear source col
    const int sswz = ((lane & 7) ^ ((lane >> 3) & 7)) * 8;   // swizzled LDS slot
    const unsigned short* Ag = xT + (rbase + srow) * K1 + schl;       // x rows (n)
    const unsigned short* Bg = W1b + (size_t)(cb + srow) * K1 + schl; // W rows (co)
    unsigned short* Xw = Xs + srow * TK + sswz;
    unsigned short* Ww = Ws + srow * TK + sswz;

    const int ln = lane & 15, q = lane >> 4;
    const int xr = (lane & 7) * 8;   // read-side XOR = (row&7)*8 with row=..+ln

    // prologue: A tile 0 into regs
    uint4 xa[4];
#pragma unroll
    for (int j = 0; j < 4; ++j) xa[j] = *(const uint4*)(Ag + (size_t)(j * 8) * K1);

    for (int k0 = 0; k0 < K1; k0 += TK) {
        const bool notlast = (k0 + TK < K1);
        // W tile for this iter (L2-resident after first touch)
        uint4 wv[4];
#pragma unroll
        for (int j = 0; j < 4; ++j) wv[j] = *(const uint4*)(Bg + (size_t)(j * 8) * K1 + k0);
        // prefetch next A tile (HBM latency overlaps ds_writes + compute below)
        uint4 xn[4];
        if (notlast) {
#pragma unroll
            for (int j = 0; j < 4; ++j) xn[j] = *(const uint4*)(Ag + (size_t)(j * 8) * K1 + k0 + TK);
        }
#pragma unroll
        for (int j = 0; j < 4; ++j) {
            *(uint4*)(Xw + (j * 8) * TK) = xa[j];
            *(uint4*)(Ww + (j * 8) * TK) = wv[j];
        }
        __syncthreads();
#pragma unroll
        for (int ks = 0; ks < 2; ++ks) {
            const int off = (q * 8 + ks * 32) ^ xr;
            v8s af[4], bx[4];
#pragma unroll
            for (int r = 0; r < 4; ++r) af[r] = *(const v8s*)(Ws + (cosub + r * 16 + ln) * TK + off);
#pragma unroll
            for (int c = 0; c < 4; ++c) bx[c] = *(const v8s*)(Xs + (nsub + c * 16 + ln) * TK + off);
#pragma unroll
            for (int r = 0; r < 4; ++r)
#pragma unroll
                for (int c = 0; c < 4; ++c)
                    acc[r][c] = __builtin_amdgcn_mfma_f32_16x16x32_bf16(af[r], bx[c], acc[r][c], 0, 0, 0);
        }
        __syncthreads();
        if (notlast) {
#pragma unroll
            for (int j = 0; j < 4; ++j) xa[j] = xn[j];
        }
    }

    // ---- epilogue: direct packed stores (lane holds 4 consecutive co) + stats
    float s[4][4], sq[4][4];
#pragma unroll
    for (int r = 0; r < 4; ++r)
#pragma unroll
        for (int i = 0; i < 4; ++i) { s[r][i] = 0.f; sq[r][i] = 0.f; }
#pragma unroll
    for (int r = 0; r < 4; ++r) {
#pragma unroll
        for (int c = 0; c < 4; ++c) {
            float v0 = acc[r][c][0], v1 = acc[r][c][1], v2 = acc[r][c][2], v3 = acc[r][c][3];
            uint2 ov;
            ov.x = (unsigned)f2bf(v0) | ((unsigned)f2bf(v1) << 16);
            ov.y = (unsigned)f2bf(v2) | ((unsigned)f2bf(v3) << 16);
            *(uint2*)&h1[(size_t)(rbase + nsub + c * 16 + ln) * CO + cb + cosub + r * 16 + q * 4] = ov;
            s[r][0] += v0; sq[r][0] += v0 * v0;
            s[r][1] += v1; sq[r][1] += v1 * v1;
            s[r][2] += v2; sq[r][2] += v2 * v2;
            s[r][3] += v3; sq[r][3] += v3 * v3;
        }
    }
    // reduce over the 16 n-lanes (xor masks stay within the q-group)
#pragma unroll
    for (int m = 1; m <= 8; m <<= 1) {
#pragma unroll
        for (int r = 0; r < 4; ++r)
#pragma unroll
            for (int i = 0; i < 4; ++i) {
                s[r][i] += __shfl_xor(s[r][i], m);
                sq[r][i] += __shfl_xor(sq[r][i], m);
            }
    }
    if (ln == 0) {
#pragma unroll
        for (int r = 0; r < 4; ++r)
#pragma unroll
            for (int i = 0; i < 4; ++i) {
                atomicAdd(&sum1[cb + cosub + r * 16 + q * 4 + i], s[r][i]);
                atomicAdd(&ssq1[cb + cosub + r * 16 + q * 4 + i], sq[r][i]);
            }
    }
}

// ====== MFMA GEMM2: h2 = relu(bn1(h1)) @ W2^T -> [B,CO,N] + BN2 stats =======
// A: reg-load (next tile prefetched) -> BN1+ReLU -> swizzled ds_write.
// B: reg-load (linear, L2-resident W2b) -> swizzled ds_write (no gload_lds).
// Direct packed n-contiguous stores + register stats.
__launch_bounds__(256)
__global__ void k_gemm2(const unsigned short* __restrict__ h1,
                        const unsigned short* __restrict__ W2b,
                        const float* __restrict__ sum1, const float* __restrict__ ssq1,
                        const float* __restrict__ g1, const float* __restrict__ b1,
                        unsigned short* __restrict__ h2,
                        float* __restrict__ sum2, float* __restrict__ ssq2) {
    __shared__ unsigned short smem[TM * TK + TN * TK];   // As | Ws
    __shared__ float sc1[CO], sh1[CO];
    unsigned short* As = smem;
    unsigned short* Ws = smem + TM * TK;
    const int t = threadIdx.x;
    const int lane = t & 63, w = t >> 6;
    const int nsub = (w >> 1) * 64;
    const int cosub = (w & 1) * 64;
    const long rbase = (long)blockIdx.x * TM;
    const int cb = blockIdx.y * TN;

    // fold BN1 finalize (stream-ordered after gemm1)
    {
        const float invn = 1.f / (float)MTOT;
        float m = sum1[t] * invn;
        float v = ssq1[t] * invn - m * m;
        float sgl = g1[t] * rsqrtf(v + 1e-5f);
        sc1[t] = sgl;
        sh1[t] = b1[t] - m * sgl;
    }
    __syncthreads();

    v4f acc[4][4];   // [r=n-tile][c=co-tile]
#pragma unroll
    for (int r = 0; r < 4; ++r)
#pragma unroll
        for (int c = 0; c < 4; ++c) acc[r][c] = (v4f)(0.f);

    const int srow = w * 32 + (lane >> 3);
    const int schl = (lane & 7) * 8;                         // linear source col
    const int sswz = ((lane & 7) ^ ((lane >> 3) & 7)) * 8;   // swizzled LDS slot
    const unsigned short* Ag = h1 + (rbase + srow) * CO + schl;
    const unsigned short* Bg = W2b + (size_t)(cb + srow) * CO + schl;
    unsigned short* Aw = As + srow * TK + sswz;
    unsigned short* Ww = Ws + srow * TK + sswz;

    // prologue: A(0) into regs
    uint4 avc[4];
#pragma unroll
    for (int j = 0; j < 4; ++j) avc[j] = *(const uint4*)(Ag + (size_t)(j * 8) * CO);

    const int ln = lane & 15, q = lane >> 4;
    const int xr = (lane & 7) * 8;

    for (int k0 = 0; k0 < CO; k0 += TK) {
        const bool notlast = (k0 + TK < CO);
        // W tile (L2-resident): reg load -> swizzled ds_write
        uint4 wv[4];
#pragma unroll
        for (int j = 0; j < 4; ++j) wv[j] = *(const uint4*)(Bg + (size_t)(j * 8) * CO + k0);
        // prefetch next A tile
        uint4 avn[4];
        if (notlast) {
#pragma unroll
            for (int j = 0; j < 4; ++j)
                avn[j] = *(const uint4*)(Ag + (size_t)(j * 8) * CO + k0 + TK);
        }
        // convert current A tile (BN1+ReLU) -> ds_write at swizzled slot
        {
            float4 sca = *(const float4*)(sc1 + k0 + schl);
            float4 scb = *(const float4*)(sc1 + k0 + schl + 4);
            float4 sha = *(const float4*)(sh1 + k0 + schl);
            float4 shb = *(const float4*)(sh1 + k0 + schl + 4);
#pragma unroll
            for (int j = 0; j < 4; ++j) {
                uint4 av = avc[j];
                float y0 = fmaxf(bf2f((unsigned short)(av.x & 0xffff)) * sca.x + sha.x, 0.f);
                float y1 = fmaxf(bf2f((unsigned short)(av.x >> 16)) * sca.y + sha.y, 0.f);
                float y2 = fmaxf(bf2f((unsigned short)(av.y & 0xffff)) * sca.z + sha.z, 0.f);
                float y3 = fmaxf(bf2f((unsigned short)(av.y >> 16)) * sca.w + sha.w, 0.f);
                float y4 = fmaxf(bf2f((unsigned short)(av.z & 0xffff)) * scb.x + shb.x, 0.f);
                float y5 = fmaxf(bf2f((unsigned short)(av.z >> 16)) * scb.y + shb.y, 0.f);
                float y6 = fmaxf(bf2f((unsigned short)(av.w & 0xffff)) * scb.z + shb.z, 0.f);
                float y7 = fmaxf(bf2f((unsigned short)(av.w >> 16)) * scb.w + shb.w, 0.f);
                uint4 ov;
                ov.x = (unsigned)f2bf(y0) | ((unsigned)f2bf(y1) << 16);
                ov.y = (unsigned)f2bf(y2) | ((unsigned)f2bf(y3) << 16);
                ov.z = (unsigned)f2bf(y4) | ((unsigned)f2bf(y5) << 16);
                ov.w = (unsigned)f2bf(y6) | ((unsigned)f2bf(y7) << 16);
                *(uint4*)(Aw + (j * 8) * TK) = ov;
            }
        }
#pragma unroll
        for (int j = 0; j < 4; ++j)
            *(uint4*)(Ww + (j * 8) * TK) = wv[j];
        __syncthreads();
#pragma unroll
        for (int ks = 0; ks < 2; ++ks) {
            const int off = (q * 8 + ks * 32) ^ xr;
            v8s af[4], bw[4];
#pragma unroll
            for (int r = 0; r < 4; ++r) af[r] = *(const v8s*)(As + (nsub + r * 16 + ln) * TK + off);
#pragma unroll
            for (int c = 0; c < 4; ++c) bw[c] = *(const v8s*)(Ws + (cosub + c * 16 + ln) * TK + off);
#pragma unroll
            for (int r = 0; r < 4; ++r)
#pragma unroll
                for (int c = 0; c < 4; ++c)
                    acc[r][c] = __builtin_amdgcn_mfma_f32_16x16x32_bf16(af[r], bw[c], acc[r][c], 0, 0, 0);
        }
        __syncthreads();
        if (notlast) {
#pragma unroll
            for (int j = 0; j < 4; ++j) avc[j] = avn[j];
        }
    }

    // ---- epilogue: direct packed stores (lane holds 4 consecutive n) + stats
    const int b = (int)(rbase >> 14);
    const int nb = (int)(rbase & (NN - 1));
#pragma unroll
    for (int c = 0; c < 4; ++c) {
        float s = 0.f, sq = 0.f;
#pragma unroll
        for (int r = 0; r < 4; ++r) {
            float v0 = acc[r][c][0], v1 = acc[r][c][1], v2 = acc[r][c][2], v3 = acc[r][c][3];
            uint2 ov;
            ov.x = (unsigned)f2bf(v0) | ((unsigned)f2bf(v1) << 16);
            ov.y = (unsigned)f2bf(v2) | ((unsigned)f2bf(v3) << 16);
            *(uint2*)&h2[(((size_t)(b * CO + cb + cosub + c * 16 + ln)) << 14) + nb + nsub + r * 16 + q * 4] = ov;
            s += v0 + v1 + v2 + v3;
            sq += v0 * v0 + v1 * v1 + v2 * v2 + v3 * v3;
        }
        s += __shfl_xor(s, 16); sq += __shfl_xor(sq, 16);
        s += __shfl_xor(s, 32); sq += __shfl_xor(sq, 32);
        if (lane < 16) {
            atomicAdd(&sum2[cb + cosub + c * 16 + lane], s);
            atomicAdd(&ssq2[cb + cosub + c * 16 + lane], sq);
        }
    }
}

// ---------------- final BN2+ReLU -> fp32 out (BN2 finalize folded) ----------
__global__ void k_apply(const unsigned short* __restrict__ h2,
                        const float* __restrict__ sum2, const float* __restrict__ ssq2,
                        const float* __restrict__ g2, const float* __restrict__ b2,
                        float* __restrict__ out) {
    __shared__ float ss[2];
    int o = (blockIdx.x >> 4) & 255;   // each block spans 1024 elems within one channel
    if (threadIdx.x == 0) {
        const float invn = 1.f / (float)MTOT;
        float m = sum2[o] * invn;
        float v = ssq2[o] * invn - m * m;
        float s = g2[o] * rsqrtf(v + 1e-5f);
        ss[0] = s;
        ss[1] = b2[o] - m * s;
    }
    __syncthreads();
    float s = ss[0], d = ss[1];
    size_t i = ((size_t)blockIdx.x * 256 + threadIdx.x) * 4;
    ushort4 hv = *(const ushort4*)(h2 + i);
    float4 v;
    v.x = fmaxf(bf2f(hv.x) * s + d, 0.f);
    v.y = fmaxf(bf2f(hv.y) * s + d, 0.f);
    v.z = fmaxf(bf2f(hv.z) * s + d, 0.f);
    v.w = fmaxf(bf2f(hv.w) * s + d, 0.f);
    *(float4*)&out[i] = v;
}

extern "C" void kernel_launch(void* const* d_in, const int* in_sizes, int n_in,
                              void* d_out, int out_size, void* d_ws, size_t ws_size,
                              hipStream_t stream) {
    const float* p1 = (const float*)d_in[0];
    const float* p2 = (const float*)d_in[1];
    const float* f1 = (const float*)d_in[2];
    const float* f2 = (const float*)d_in[3];
    const void*  idx = d_in[4];
    const float* W1 = (const float*)d_in[5];
    const float* g1 = (const float*)d_in[6];
    const float* b1 = (const float*)d_in[7];
    const float* W2 = (const float*)d_in[8];
    const float* g2 = (const float*)d_in[9];
    const float* b2 = (const float*)d_in[10];
    float* out = (float*)d_out;

    char* ws = (char*)d_ws;
    float* stats = (float*)(ws + STATS_OFF);
    float* sum1 = stats + 0;     float* ssq1 = stats + 256;
    float* sum2 = stats + 1024;  float* ssq2 = stats + 1280;
    int* flag64 = (int*)(ws + FLAG_OFF);
    unsigned short* W1b = (unsigned short*)(ws + W1B_OFF);
    unsigned short* W2b = (unsigned short*)(ws + W2B_OFF);
    unsigned short* f2t = (unsigned short*)(ws + F2T_OFF);
    unsigned short* xT  = (unsigned short*)(ws + XT_OFF);
    unsigned short* h2  = (unsigned short*)(ws + H2_OFF);

    unsigned short* h1 = (unsigned short*)d_out;  // 67 MB bf16 scratch in d_out

    k_prep<<<577, 256, 0, stream>>>(idx, flag64, stats, W1, W1b, W2, W2b);
    k_tr_f2<<<dim3(MM / 32, C2 / 64, BB), 256, 0, stream>>>(f2, f2t);
    k_tr_f1<<<dim3(NN / 32, 1, BB), 256, 0, stream>>>(f1, xT);
    k_interp<<<MTOT / 8, 256, 0, stream>>>(p1, p2, idx, flag64, f2t, xT);
    k_gemm1<<<dim3(MTOT / TM, CO / TN), 256, 0, stream>>>(xT, W1b, h1, sum1, ssq1);
    k_gemm2<<<dim3(MTOT / TM, CO / TN), 256, 0, stream>>>(h1, W2b, sum1, ssq1, g1, b1, h2, sum2, ssq2);
    k_apply<<<(int)((size_t)out_size / 4 / 256), 256, 0, stream>>>(h2, sum2, ssq2, g2, b2, out);
}

// Round 4
// 423.111 us; speedup vs baseline: 1.7392x; 1.7392x over previous
//
#include <hip/hip_runtime.h>
#include <hip/hip_bf16.h>

// Problem constants
#define BB 8
#define NN 16384
#define MM 4096
#define C1 64
#define C2 256
#define K1 320            // C1 + C2
#define CO 256
#define MTOT (BB * NN)    // 131072

// Workspace layout (bytes)
#define STATS_OFF 0                 // 8*256 floats
#define FLAG_OFF  8192
#define W1B_OFF   16384             // bf16 256x320
#define W2B_OFF   180224            // bf16 256x256
#define F2T_OFF   327680            // bf16 [B,M,C2] = 16777216 B
#define XT_OFF    (327680 + 16777216)              // bf16 [MTOT,320]
#define H2_OFF    (327680 + 16777216 + 83886080)   // bf16 [B,CO,N]

// Global column-chunk swizzle: within each 64-col (8-chunk) group, the 16B
// chunk c of row r is stored at chunk c ^ (r&7). Linear-source global_load_lds
// (monotone lane addresses - the r1/r2 swizzled-source DMA was 4x poison)
// then lands a bank-conflict-free layout in LDS; fragment reads XOR back.

typedef short v8s __attribute__((ext_vector_type(8)));
typedef float v4f __attribute__((ext_vector_type(4)));

__device__ __forceinline__ float bf2f(unsigned short u) {
    unsigned v = ((unsigned)u) << 16;
    float f;
    __builtin_memcpy(&f, &v, 4);
    return f;
}
__device__ __forceinline__ unsigned short f2bf(float f) {
    unsigned u;
    __builtin_memcpy(&u, &f, 4);
    unsigned r = u + 0x7fffu + ((u >> 16) & 1u);  // RNE
    return (unsigned short)(r >> 16);
}
__device__ __forceinline__ void gload16(const unsigned short* g, unsigned short* l) {
    __builtin_amdgcn_global_load_lds((const __attribute__((address_space(1))) unsigned int*)g,
                                     (__attribute__((address_space(3))) unsigned int*)l, 16, 0, 0);
}

// ---------------- prep: zero stats, idx width flag, W1/W2 -> bf16 ----------
// Weights stored column-chunk-swizzled: col' = col ^ ((row&7)<<3).
__global__ void k_prep(const void* idx_raw, int* flag64, float* stats,
                       const float* __restrict__ W1, unsigned short* __restrict__ W1b,
                       const float* __restrict__ W2, unsigned short* __restrict__ W2b) {
    int blk = blockIdx.x;
    int t = threadIdx.x;
    if (blk < 320) {
        int e = blk * 256 + t;
        int row = e / K1, col = e - row * K1;
        W1b[row * K1 + (col ^ ((row & 7) << 3))] = f2bf(W1[e]);
    } else if (blk < 576) {
        int e = (blk - 320) * 256 + t;
        int row = e >> 8, col = e & 255;
        W2b[row * CO + (col ^ ((row & 7) << 3))] = f2bf(W2[e]);
    } else {
        for (int i = t; i < 8 * 256; i += 256) stats[i] = 0.f;
        if (t == 0) {
            const int* a = (const int*)idx_raw;
            int all0 = 1;
            for (int j = 1; j < 64; j += 2) all0 &= (a[j] == 0);
            *flag64 = all0;  // 1 => idx int64
        }
    }
}

// ------- transpose f2 [B,C2,M] -> f2t bf16 [B,M,C2]; 64ch x 32m tiles ------
// (f2t is consumed row-wise by k_interp only - no swizzle)
__global__ void k_tr_f2(const float* __restrict__ f2, unsigned short* __restrict__ f2t) {
    __shared__ float tile[64][33];
    int b = blockIdx.z;
    int c0 = blockIdx.y * 64;
    int m0 = blockIdx.x * 32;
    int t = threadIdx.x;
    int lm = t & 31, lc = t >> 5;          // lc 0..7
    const float* src = f2 + ((size_t)b * C2 + c0) * MM + m0;
#pragma unroll
    for (int j = 0; j < 8; ++j)
        tile[lc + 8 * j][lm] = src[(size_t)(lc + 8 * j) * MM + lm];
    __syncthreads();
    int m = t >> 3, c8 = (t & 7) * 8;      // m 0..31, c8 0..56
    unsigned short tmp[8];
#pragma unroll
    for (int k = 0; k < 8; ++k) tmp[k] = f2bf(tile[c8 + k][m]);
    uint4 v;
    v.x = (unsigned)tmp[0] | ((unsigned)tmp[1] << 16);
    v.y = (unsigned)tmp[2] | ((unsigned)tmp[3] << 16);
    v.z = (unsigned)tmp[4] | ((unsigned)tmp[5] << 16);
    v.w = (unsigned)tmp[6] | ((unsigned)tmp[7] << 16);
    *(uint4*)&f2t[((size_t)b * MM + m0 + m) * C2 + c0 + c8] = v;
}

// ------- transpose f1 [B,C1,N] -> xT[:,0:64] bf16; 64ch x 32n tiles --------
// xT stored chunk-swizzled by row: chunk' = chunk ^ (n&7) within the group.
__global__ void k_tr_f1(const float* __restrict__ f1, unsigned short* __restrict__ xT) {
    __shared__ float tile[64][33];
    int b = blockIdx.z;
    int n0 = blockIdx.x * 32;
    int t = threadIdx.x;
    int lm = t & 31, lc = t >> 5;
    const float* src = f1 + ((size_t)b * C1) * NN + n0;
#pragma unroll
    for (int j = 0; j < 8; ++j)
        tile[lc + 8 * j][lm] = src[(size_t)(lc + 8 * j) * NN + lm];
    __syncthreads();
    int m = t >> 3, c8 = (t & 7) * 8;
    unsigned short tmp[8];
#pragma unroll
    for (int k = 0; k < 8; ++k) tmp[k] = f2bf(tile[c8 + k][m]);
    uint4 v;
    v.x = (unsigned)tmp[0] | ((unsigned)tmp[1] << 16);
    v.y = (unsigned)tmp[2] | ((unsigned)tmp[3] << 16);
    v.z = (unsigned)tmp[4] | ((unsigned)tmp[5] << 16);
    v.w = (unsigned)tmp[6] | ((unsigned)tmp[7] << 16);
    // row = n0+m; (row&7) == (m&7) since n0 % 32 == 0
    *(uint4*)&xT[((size_t)b * NN + n0 + m) * K1 + (c8 ^ ((m & 7) * 8))] = v;
}

// ---------------- 3-NN inverse-distance interpolation -> xT[:,64:320] -------
__global__ void k_interp(const float* __restrict__ p1, const float* __restrict__ p2,
                         const void* __restrict__ idxv, const int* __restrict__ flag64,
                         const unsigned short* __restrict__ f2t,
                         unsigned short* __restrict__ xT) {
    int t = threadIdx.x;
    int p = t >> 5, lane = t & 31;
    size_t pt = (size_t)blockIdx.x * 8 + p;
    int b = (int)(pt >> 14);
    int m0, m1, m2;
    if (*flag64) {
        const long long* id = (const long long*)idxv;
        m0 = (int)id[pt * 3 + 0]; m1 = (int)id[pt * 3 + 1]; m2 = (int)id[pt * 3 + 2];
    } else {
        const int* id = (const int*)idxv;
        m0 = id[pt * 3 + 0]; m1 = id[pt * 3 + 1]; m2 = id[pt * 3 + 2];
    }
    float qx = p1[pt * 3 + 0], qy = p1[pt * 3 + 1], qz = p1[pt * 3 + 2];
    const float* pb = p2 + (size_t)b * MM * 3;
    float dx, dy, dz;
    dx = qx - pb[m0 * 3 + 0]; dy = qy - pb[m0 * 3 + 1]; dz = qz - pb[m0 * 3 + 2];
    float d0 = dx * dx + dy * dy + dz * dz;
    dx = qx - pb[m1 * 3 + 0]; dy = qy - pb[m1 * 3 + 1]; dz = qz - pb[m1 * 3 + 2];
    float d1 = dx * dx + dy * dy + dz * dz;
    dx = qx - pb[m2 * 3 + 0]; dy = qy - pb[m2 * 3 + 1]; dz = qz - pb[m2 * 3 + 2];
    float d2v = dx * dx + dy * dy + dz * dz;
    float r0 = 1.f / (d0 + 1e-8f), r1 = 1.f / (d1 + 1e-8f), r2 = 1.f / (d2v + 1e-8f);
    float inv = 1.f / (r0 + r1 + r2);
    float w0 = r0 * inv, w1 = r1 * inv, w2 = r2 * inv;

    const unsigned short* fb = f2t + (size_t)b * MM * C2;
    int c0 = lane * 8;
    uint4 va = *(const uint4*)(fb + (size_t)m0 * C2 + c0);
    uint4 vb = *(const uint4*)(fb + (size_t)m1 * C2 + c0);
    uint4 vc = *(const uint4*)(fb + (size_t)m2 * C2 + c0);

    float r[8];
    {
        const unsigned av[4] = {va.x, va.y, va.z, va.w};
        const unsigned bv[4] = {vb.x, vb.y, vb.z, vb.w};
        const unsigned cv[4] = {vc.x, vc.y, vc.z, vc.w};
#pragma unroll
        for (int q = 0; q < 4; ++q) {
            r[2 * q + 0] = w0 * bf2f((unsigned short)(av[q] & 0xffff))
                         + w1 * bf2f((unsigned short)(bv[q] & 0xffff))
                         + w2 * bf2f((unsigned short)(cv[q] & 0xffff));
            r[2 * q + 1] = w0 * bf2f((unsigned short)(av[q] >> 16))
                         + w1 * bf2f((unsigned short)(bv[q] >> 16))
                         + w2 * bf2f((unsigned short)(cv[q] >> 16));
        }
    }
    uint4 outv;
    outv.x = (unsigned)f2bf(r[0]) | ((unsigned)f2bf(r[1]) << 16);
    outv.y = (unsigned)f2bf(r[2]) | ((unsigned)f2bf(r[3]) << 16);
    outv.z = (unsigned)f2bf(r[4]) | ((unsigned)f2bf(r[5]) << 16);
    outv.w = (unsigned)f2bf(r[6]) | ((unsigned)f2bf(r[7]) << 16);
    // chunk-swizzle by point row: col' = col ^ ((pt&7)*8) (stays in 64-col group)
    *(uint4*)(xT + pt * K1 + ((C1 + c0) ^ (((int)pt & 7) * 8))) = outv;
}

// ================= MFMA GEMM1: h1 = xT @ W1^T (bf16), + BN1 stats ==========
// r0-identical staging/schedule (linear-source gload_lds, stage->sync->
// compute->sync). Inputs pre-swizzled in global => LDS is conflict-free;
// fragment reads XOR the chunk index by (row&7).
#define TM 128
#define TN 128
#define TK 64
__launch_bounds__(256)
__global__ void k_gemm1(const unsigned short* __restrict__ xT,
                        const unsigned short* __restrict__ W1b,
                        unsigned short* __restrict__ h1,
                        float* __restrict__ sum1, float* __restrict__ ssq1) {
    __shared__ unsigned short smem[TM * TK + TN * TK];   // As | Bs, reused as 128x128 epilogue tile
    __shared__ float s_sum[TN], s_ssq[TN];
    unsigned short* As = smem;
    unsigned short* Bs = smem + TM * TK;
    const int t = threadIdx.x;
    const int lane = t & 63, w = t >> 6;
    const int wm = w >> 1, wc = w & 1;
    const long rbase = (long)blockIdx.x * TM;
    const int cb = blockIdx.y * TN;

    if (t < TN) { s_sum[t] = 0.f; s_ssq[t] = 0.f; }

    v4f acc[4][4];
#pragma unroll
    for (int r = 0; r < 4; ++r)
#pragma unroll
        for (int c = 0; c < 4; ++c) acc[r][c] = (v4f)(0.f);

    const int srow = w * 32 + (lane >> 3);
    const int sch = (lane & 7) * 8;          // LINEAR source col (monotone DMA)
    const unsigned short* Ag = xT + (rbase + srow) * K1 + sch;
    const unsigned short* Bg = W1b + (size_t)(cb + srow) * K1 + sch;

    const int ln = lane & 15, q = lane >> 4;
    const int xs = (ln & 7) * 8;             // read-side XOR: (row&7)*8

    for (int k0 = 0; k0 < K1; k0 += TK) {
#pragma unroll
        for (int j = 0; j < 4; ++j) {
            gload16(Ag + (size_t)(j * 8) * K1 + k0, As + (w * 32 + j * 8) * TK);
            gload16(Bg + (size_t)(j * 8) * K1 + k0, Bs + (w * 32 + j * 8) * TK);
        }
        __syncthreads();
        const unsigned short* ApL = As + (wm * 64 + ln) * TK;
        const unsigned short* BpL = Bs + (wc * 64 + ln) * TK;
#pragma unroll
        for (int ks = 0; ks < 2; ++ks) {
            const int off = (q * 8 + ks * 32) ^ xs;
            v8s af[4], bg[4];
#pragma unroll
            for (int r = 0; r < 4; ++r) af[r] = *(const v8s*)(ApL + r * 16 * TK + off);
#pragma unroll
            for (int c = 0; c < 4; ++c) bg[c] = *(const v8s*)(BpL + c * 16 * TK + off);
#pragma unroll
            for (int r = 0; r < 4; ++r)
#pragma unroll
                for (int c = 0; c < 4; ++c)
                    acc[r][c] = __builtin_amdgcn_mfma_f32_16x16x32_bf16(af[r], bg[c], acc[r][c], 0, 0, 0);
        }
        __syncthreads();
    }

    // ---- epilogue: stats + XOR-swizzled LDS transpose -> coalesced stores ----
#pragma unroll
    for (int c = 0; c < 4; ++c) {
        int col = wc * 64 + c * 16 + ln;            // local col 0..127
        int cc = col >> 3, ci = col & 7;
        float s = 0.f, sq = 0.f;
#pragma unroll
        for (int r = 0; r < 4; ++r)
#pragma unroll
            for (int i = 0; i < 4; ++i) {
                int row = wm * 64 + r * 16 + q * 4 + i;
                float v = acc[r][c][i];
                smem[row * 128 + 8 * (cc ^ (row & 15)) + ci] = f2bf(v);
                s += v; sq += v * v;
            }
        atomicAdd(&s_sum[col], s);
        atomicAdd(&s_ssq[col], sq);
    }
    __syncthreads();
    {
        int rr = t >> 4, cc2 = t & 15;
#pragma unroll
        for (int j = 0; j < 8; ++j) {
            int row = rr + 16 * j;
            uint4 v = *(const uint4*)&smem[row * 128 + 8 * (cc2 ^ (row & 15))];
            *(uint4*)&h1[(size_t)(rbase + row) * CO + cb + cc2 * 8] = v;
        }
    }
    if (t < TN) {
        atomicAdd(&sum1[cb + t], s_sum[t]);
        atomicAdd(&ssq1[cb + t], s_ssq[t]);
    }
}

// ====== MFMA GEMM2: h2 = relu(bn1(h1)) @ W2^T -> [B,CO,N] + BN2 stats =======
// r0-identical schedule. A: reg-load (next tile prefetched) -> BN1+ReLU ->
// ds_write at chunk-swizzled slot. B: W2b pre-swizzled in global, linear DMA.
// Fragment reads XOR by (row&7).
__launch_bounds__(256)
__global__ void k_gemm2(const unsigned short* __restrict__ h1,
                        const unsigned short* __restrict__ W2b,
                        const float* __restrict__ sum1, const float* __restrict__ ssq1,
                        const float* __restrict__ g1, const float* __restrict__ b1,
                        unsigned short* __restrict__ h2,
                        float* __restrict__ sum2, float* __restrict__ ssq2) {
    __shared__ unsigned short smem[TM * TK + TN * TK];
    __shared__ float s_sum[TN], s_ssq[TN];
    __shared__ float sc1[CO], sh1[CO];
    unsigned short* As = smem;
    unsigned short* Bs = smem + TM * TK;
    const int t = threadIdx.x;
    const int lane = t & 63, w = t >> 6;
    const int wm = w >> 1, wc = w & 1;
    const long rbase = (long)blockIdx.x * TM;
    const int cb = blockIdx.y * TN;

    // fold BN1 finalize: per-block compute of scale/shift (stream-ordered after gemm1)
    {
        const float invn = 1.f / (float)MTOT;
        float m = sum1[t] * invn;
        float v = ssq1[t] * invn - m * m;
        float s = g1[t] * rsqrtf(v + 1e-5f);
        sc1[t] = s;
        sh1[t] = b1[t] - m * s;
    }
    if (t < TN) { s_sum[t] = 0.f; s_ssq[t] = 0.f; }
    __syncthreads();

    v4f acc[4][4];
#pragma unroll
    for (int r = 0; r < 4; ++r)
#pragma unroll
        for (int c = 0; c < 4; ++c) acc[r][c] = (v4f)(0.f);

    const int srow = w * 32 + (lane >> 3);
    const int sch = (lane & 7) * 8;
    const unsigned short* Ag = h1 + (rbase + srow) * CO + sch;
    const unsigned short* Bg = W2b + (size_t)(cb + srow) * CO + sch;
    // A ds_write at chunk-swizzled slot (matches read-side XOR)
    unsigned short* AsW = As + srow * TK + (sch ^ ((srow & 7) * 8));

    for (int k0 = 0; k0 < CO; k0 += TK) {
#pragma unroll
        for (int j = 0; j < 4; ++j)
            gload16(Bg + (size_t)(j * 8) * CO + k0, Bs + (w * 32 + j * 8) * TK);
        float4 sca = *(const float4*)(sc1 + k0 + sch);
        float4 scb = *(const float4*)(sc1 + k0 + sch + 4);
        float4 sha = *(const float4*)(sh1 + k0 + sch);
        float4 shb = *(const float4*)(sh1 + k0 + sch + 4);
#pragma unroll
        for (int j = 0; j < 4; ++j) {
            uint4 av = *(const uint4*)(Ag + (size_t)(j * 8) * CO + k0);
            float y0 = fmaxf(bf2f((unsigned short)(av.x & 0xffff)) * sca.x + sha.x, 0.f);
            float y1 = fmaxf(bf2f((unsigned short)(av.x >> 16)) * sca.y + sha.y, 0.f);
            float y2 = fmaxf(bf2f((unsigned short)(av.y & 0xffff)) * sca.z + sha.z, 0.f);
            float y3 = fmaxf(bf2f((unsigned short)(av.y >> 16)) * sca.w + sha.w, 0.f);
            float y4 = fmaxf(bf2f((unsigned short)(av.z & 0xffff)) * scb.x + shb.x, 0.f);
            float y5 = fmaxf(bf2f((unsigned short)(av.z >> 16)) * scb.y + shb.y, 0.f);
            float y6 = fmaxf(bf2f((unsigned short)(av.w & 0xffff)) * scb.z + shb.z, 0.f);
            float y7 = fmaxf(bf2f((unsigned short)(av.w >> 16)) * scb.w + shb.w, 0.f);
            uint4 ov;
            ov.x = (unsigned)f2bf(y0) | ((unsigned)f2bf(y1) << 16);
            ov.y = (unsigned)f2bf(y2) | ((unsigned)f2bf(y3) << 16);
            ov.z = (unsigned)f2bf(y4) | ((unsigned)f2bf(y5) << 16);
            ov.w = (unsigned)f2bf(y6) | ((unsigned)f2bf(y7) << 16);
            *(uint4*)(AsW + (j * 8) * TK) = ov;
        }
        __syncthreads();
        const int ln = lane & 15, q = lane >> 4;
        const int xs = (ln & 7) * 8;
        const unsigned short* ApL = As + (wm * 64 + ln) * TK;
        const unsigned short* BpL = Bs + (wc * 64 + ln) * TK;
#pragma unroll
        for (int ks = 0; ks < 2; ++ks) {
            const int off = (q * 8 + ks * 32) ^ xs;
            v8s af[4], bg4[4];
#pragma unroll
            for (int r = 0; r < 4; ++r) af[r] = *(const v8s*)(ApL + r * 16 * TK + off);
#pragma unroll
            for (int c = 0; c < 4; ++c) bg4[c] = *(const v8s*)(BpL + c * 16 * TK + off);
#pragma unroll
            for (int r = 0; r < 4; ++r)
#pragma unroll
                for (int c = 0; c < 4; ++c)
                    acc[r][c] = __builtin_amdgcn_mfma_f32_16x16x32_bf16(af[r], bg4[c], acc[r][c], 0, 0, 0);
        }
        __syncthreads();
    }

    // ---- epilogue: stats + transposed swizzled tile -> n-contiguous stores ----
    const int q = lane >> 4, ln = lane & 15;
    const int b = (int)(rbase >> 14);
    const int nb = (int)(rbase & (NN - 1));
#pragma unroll
    for (int c = 0; c < 4; ++c) {
        int ol = wc * 64 + c * 16 + ln;             // local out-channel 0..127
        float s = 0.f, sq = 0.f;
#pragma unroll
        for (int r = 0; r < 4; ++r)
#pragma unroll
            for (int i = 0; i < 4; ++i) {
                int row = wm * 64 + r * 16 + q * 4 + i;  // local n
                int rc = row >> 3, ri = row & 7;
                float v = acc[r][c][i];
                smem[ol * 128 + 8 * (rc ^ (ol & 15)) + ri] = f2bf(v);
                s += v; sq += v * v;
            }
        atomicAdd(&s_sum[ol], s);
        atomicAdd(&s_ssq[ol], sq);
    }
    __syncthreads();
    {
        int oo = t >> 4, nc = t & 15;
#pragma unroll
        for (int j = 0; j < 8; ++j) {
            int ol = oo + 16 * j;
            uint4 v = *(const uint4*)&smem[ol * 128 + 8 * (nc ^ (ol & 15))];
            *(uint4*)&h2[(((size_t)(b * CO + cb + ol)) << 14) + nb + nc * 8] = v;
        }
    }
    if (t < TN) {
        atomicAdd(&sum2[cb + t], s_sum[t]);
        atomicAdd(&ssq2[cb + t], s_ssq[t]);
    }
}

// ---------------- final BN2+ReLU -> fp32 out (BN2 finalize folded) ----------
__global__ void k_apply(const unsigned short* __restrict__ h2,
                        const float* __restrict__ sum2, const float* __restrict__ ssq2,
                        const float* __restrict__ g2, const float* __restrict__ b2,
                        float* __restrict__ out) {
    __shared__ float ss[2];
    int o = (blockIdx.x >> 4) & 255;   // each block spans 1024 elems within one channel
    if (threadIdx.x == 0) {
        const float invn = 1.f / (float)MTOT;
        float m = sum2[o] * invn;
        float v = ssq2[o] * invn - m * m;
        float s = g2[o] * rsqrtf(v + 1e-5f);
        ss[0] = s;
        ss[1] = b2[o] - m * s;
    }
    __syncthreads();
    float s = ss[0], d = ss[1];
    size_t i = ((size_t)blockIdx.x * 256 + threadIdx.x) * 4;
    ushort4 hv = *(const ushort4*)(h2 + i);
    float4 v;
    v.x = fmaxf(bf2f(hv.x) * s + d, 0.f);
    v.y = fmaxf(bf2f(hv.y) * s + d, 0.f);
    v.z = fmaxf(bf2f(hv.z) * s + d, 0.f);
    v.w = fmaxf(bf2f(hv.w) * s + d, 0.f);
    *(float4*)&out[i] = v;
}

extern "C" void kernel_launch(void* const* d_in, const int* in_sizes, int n_in,
                              void* d_out, int out_size, void* d_ws, size_t ws_size,
                              hipStream_t stream) {
    const float* p1 = (const float*)d_in[0];
    const float* p2 = (const float*)d_in[1];
    const float* f1 = (const float*)d_in[2];
    const float* f2 = (const float*)d_in[3];
    const void*  idx = d_in[4];
    const float* W1 = (const float*)d_in[5];
    const float* g1 = (const float*)d_in[6];
    const float* b1 = (const float*)d_in[7];
    const float* W2 = (const float*)d_in[8];
    const float* g2 = (const float*)d_in[9];
    const float* b2 = (const float*)d_in[10];
    float* out = (float*)d_out;

    char* ws = (char*)d_ws;
    float* stats = (float*)(ws + STATS_OFF);
    float* sum1 = stats + 0;     float* ssq1 = stats + 256;
    float* sum2 = stats + 1024;  float* ssq2 = stats + 1280;
    int* flag64 = (int*)(ws + FLAG_OFF);
    unsigned short* W1b = (unsigned short*)(ws + W1B_OFF);
    unsigned short* W2b = (unsigned short*)(ws + W2B_OFF);
    unsigned short* f2t = (unsigned short*)(ws + F2T_OFF);
    unsigned short* xT  = (unsigned short*)(ws + XT_OFF);
    unsigned short* h2  = (unsigned short*)(ws + H2_OFF);

    unsigned short* h1 = (unsigned short*)d_out;  // 67 MB bf16 scratch in d_out

    k_prep<<<577, 256, 0, stream>>>(idx, flag64, stats, W1, W1b, W2, W2b);
    k_tr_f2<<<dim3(MM / 32, C2 / 64, BB), 256, 0, stream>>>(f2, f2t);
    k_tr_f1<<<dim3(NN / 32, 1, BB), 256, 0, stream>>>(f1, xT);
    k_interp<<<MTOT / 8, 256, 0, stream>>>(p1, p2, idx, flag64, f2t, xT);
    k_gemm1<<<dim3(MTOT / TM, CO / TN), 256, 0, stream>>>(xT, W1b, h1, sum1, ssq1);
    k_gemm2<<<dim3(MTOT / TM, CO / TN), 256, 0, stream>>>(h1, W2b, sum1, ssq1, g1, b1, h2, sum2, ssq2);
    k_apply<<<(int)((size_t)out_size / 4 / 256), 256, 0, stream>>>(h2, sum2, ssq2, g2, b2, out);
}

// Round 6
// 405.763 us; speedup vs baseline: 1.8136x; 1.0428x over previous
//
#include <hip/hip_runtime.h>
#include <hip/hip_bf16.h>

// Problem constants
#define BB 8
#define NN 16384
#define MM 4096
#define C1 64
#define C2 256
#define K1 320            // C1 + C2
#define CO 256
#define MTOT (BB * NN)    // 131072

// Workspace layout (bytes)
#define STATS_OFF 0                 // 8*256 floats
#define FLAG_OFF  8192
#define W1B_OFF   16384             // bf16 256x320
#define W2B_OFF   180224            // bf16 256x256
#define F2T_OFF   327680            // bf16 [B,M,C2] = 16777216 B
#define XT_OFF    (327680 + 16777216)              // bf16 [MTOT,320]
#define H2_OFF    (327680 + 16777216 + 83886080)   // bf16 [B,CO,N]

// Global column-chunk swizzle: within each 64-col (8-chunk) group, the 16B
// chunk c of row r is stored at chunk c ^ (r&7). Linear-source global_load_lds
// (monotone lane addresses - swizzled-source DMA was the r1/r2 4x poison)
// lands a bank-conflict-free layout in LDS; fragment reads XOR back.
// r6: gemm1 uses a plain-__syncthreads 2-phase double buffer (issue next tile
// -> compute current -> sync). Counted-vmcnt/raw-barrier is BANNED (r5 raced).

typedef short v8s __attribute__((ext_vector_type(8)));
typedef float v4f __attribute__((ext_vector_type(4)));

__device__ __forceinline__ float bf2f(unsigned short u) {
    unsigned v = ((unsigned)u) << 16;
    float f;
    __builtin_memcpy(&f, &v, 4);
    return f;
}
__device__ __forceinline__ unsigned short f2bf(float f) {
    unsigned u;
    __builtin_memcpy(&u, &f, 4);
    unsigned r = u + 0x7fffu + ((u >> 16) & 1u);  // RNE
    return (unsigned short)(r >> 16);
}
__device__ __forceinline__ void gload16(const unsigned short* g, unsigned short* l) {
    __builtin_amdgcn_global_load_lds((const __attribute__((address_space(1))) unsigned int*)g,
                                     (__attribute__((address_space(3))) unsigned int*)l, 16, 0, 0);
}

// ---------------- prep: zero stats, idx width flag, W1/W2 -> bf16 ----------
// Weights stored column-chunk-swizzled: col' = col ^ ((row&7)<<3).
__global__ void k_prep(const void* idx_raw, int* flag64, float* stats,
                       const float* __restrict__ W1, unsigned short* __restrict__ W1b,
                       const float* __restrict__ W2, unsigned short* __restrict__ W2b) {
    int blk = blockIdx.x;
    int t = threadIdx.x;
    if (blk < 320) {
        int e = blk * 256 + t;
        int row = e / K1, col = e - row * K1;
        W1b[row * K1 + (col ^ ((row & 7) << 3))] = f2bf(W1[e]);
    } else if (blk < 576) {
        int e = (blk - 320) * 256 + t;
        int row = e >> 8, col = e & 255;
        W2b[row * CO + (col ^ ((row & 7) << 3))] = f2bf(W2[e]);
    } else {
        for (int i = t; i < 8 * 256; i += 256) stats[i] = 0.f;
        if (t == 0) {
            const int* a = (const int*)idx_raw;
            int all0 = 1;
            for (int j = 1; j < 64; j += 2) all0 &= (a[j] == 0);
            *flag64 = all0;  // 1 => idx int64
        }
    }
}

// ------- transpose f2 [B,C2,M] -> f2t bf16 [B,M,C2]; 64ch x 32m tiles ------
__global__ void k_tr_f2(const float* __restrict__ f2, unsigned short* __restrict__ f2t) {
    __shared__ float tile[64][33];
    int b = blockIdx.z;
    int c0 = blockIdx.y * 64;
    int m0 = blockIdx.x * 32;
    int t = threadIdx.x;
    int lm = t & 31, lc = t >> 5;          // lc 0..7
    const float* src = f2 + ((size_t)b * C2 + c0) * MM + m0;
#pragma unroll
    for (int j = 0; j < 8; ++j)
        tile[lc + 8 * j][lm] = src[(size_t)(lc + 8 * j) * MM + lm];
    __syncthreads();
    int m = t >> 3, c8 = (t & 7) * 8;      // m 0..31, c8 0..56
    unsigned short tmp[8];
#pragma unroll
    for (int k = 0; k < 8; ++k) tmp[k] = f2bf(tile[c8 + k][m]);
    uint4 v;
    v.x = (unsigned)tmp[0] | ((unsigned)tmp[1] << 16);
    v.y = (unsigned)tmp[2] | ((unsigned)tmp[3] << 16);
    v.z = (unsigned)tmp[4] | ((unsigned)tmp[5] << 16);
    v.w = (unsigned)tmp[6] | ((unsigned)tmp[7] << 16);
    *(uint4*)&f2t[((size_t)b * MM + m0 + m) * C2 + c0 + c8] = v;
}

// ------- transpose f1 [B,C1,N] -> xT[:,0:64] bf16; 64ch x 32n tiles --------
// xT stored chunk-swizzled by row: chunk' = chunk ^ (n&7) within the group.
__global__ void k_tr_f1(const float* __restrict__ f1, unsigned short* __restrict__ xT) {
    __shared__ float tile[64][33];
    int b = blockIdx.z;
    int n0 = blockIdx.x * 32;
    int t = threadIdx.x;
    int lm = t & 31, lc = t >> 5;
    const float* src = f1 + ((size_t)b * C1) * NN + n0;
#pragma unroll
    for (int j = 0; j < 8; ++j)
        tile[lc + 8 * j][lm] = src[(size_t)(lc + 8 * j) * NN + lm];
    __syncthreads();
    int m = t >> 3, c8 = (t & 7) * 8;
    unsigned short tmp[8];
#pragma unroll
    for (int k = 0; k < 8; ++k) tmp[k] = f2bf(tile[c8 + k][m]);
    uint4 v;
    v.x = (unsigned)tmp[0] | ((unsigned)tmp[1] << 16);
    v.y = (unsigned)tmp[2] | ((unsigned)tmp[3] << 16);
    v.z = (unsigned)tmp[4] | ((unsigned)tmp[5] << 16);
    v.w = (unsigned)tmp[6] | ((unsigned)tmp[7] << 16);
    // row = n0+m; (row&7) == (m&7) since n0 % 32 == 0
    *(uint4*)&xT[((size_t)b * NN + n0 + m) * K1 + (c8 ^ ((m & 7) * 8))] = v;
}

// ---------------- 3-NN inverse-distance interpolation -> xT[:,64:320] -------
__global__ void k_interp(const float* __restrict__ p1, const float* __restrict__ p2,
                         const void* __restrict__ idxv, const int* __restrict__ flag64,
                         const unsigned short* __restrict__ f2t,
                         unsigned short* __restrict__ xT) {
    int t = threadIdx.x;
    int p = t >> 5, lane = t & 31;
    size_t pt = (size_t)blockIdx.x * 8 + p;
    int b = (int)(pt >> 14);
    int m0, m1, m2;
    if (*flag64) {
        const long long* id = (const long long*)idxv;
        m0 = (int)id[pt * 3 + 0]; m1 = (int)id[pt * 3 + 1]; m2 = (int)id[pt * 3 + 2];
    } else {
        const int* id = (const int*)idxv;
        m0 = id[pt * 3 + 0]; m1 = id[pt * 3 + 1]; m2 = id[pt * 3 + 2];
    }
    float qx = p1[pt * 3 + 0], qy = p1[pt * 3 + 1], qz = p1[pt * 3 + 2];
    const float* pb = p2 + (size_t)b * MM * 3;
    float dx, dy, dz;
    dx = qx - pb[m0 * 3 + 0]; dy = qy - pb[m0 * 3 + 1]; dz = qz - pb[m0 * 3 + 2];
    float d0 = dx * dx + dy * dy + dz * dz;
    dx = qx - pb[m1 * 3 + 0]; dy = qy - pb[m1 * 3 + 1]; dz = qz - pb[m1 * 3 + 2];
    float d1 = dx * dx + dy * dy + dz * dz;
    dx = qx - pb[m2 * 3 + 0]; dy = qy - pb[m2 * 3 + 1]; dz = qz - pb[m2 * 3 + 2];
    float d2v = dx * dx + dy * dy + dz * dz;
    float r0 = 1.f / (d0 + 1e-8f), r1 = 1.f / (d1 + 1e-8f), r2 = 1.f / (d2v + 1e-8f);
    float inv = 1.f / (r0 + r1 + r2);
    float w0 = r0 * inv, w1 = r1 * inv, w2 = r2 * inv;

    const unsigned short* fb = f2t + (size_t)b * MM * C2;
    int c0 = lane * 8;
    uint4 va = *(const uint4*)(fb + (size_t)m0 * C2 + c0);
    uint4 vb = *(const uint4*)(fb + (size_t)m1 * C2 + c0);
    uint4 vc = *(const uint4*)(fb + (size_t)m2 * C2 + c0);

    float r[8];
    {
        const unsigned av[4] = {va.x, va.y, va.z, va.w};
        const unsigned bv[4] = {vb.x, vb.y, vb.z, vb.w};
        const unsigned cv[4] = {vc.x, vc.y, vc.z, vc.w};
#pragma unroll
        for (int q = 0; q < 4; ++q) {
            r[2 * q + 0] = w0 * bf2f((unsigned short)(av[q] & 0xffff))
                         + w1 * bf2f((unsigned short)(bv[q] & 0xffff))
                         + w2 * bf2f((unsigned short)(cv[q] & 0xffff));
            r[2 * q + 1] = w0 * bf2f((unsigned short)(av[q] >> 16))
                         + w1 * bf2f((unsigned short)(bv[q] >> 16))
                         + w2 * bf2f((unsigned short)(cv[q] >> 16));
        }
    }
    uint4 outv;
    outv.x = (unsigned)f2bf(r[0]) | ((unsigned)f2bf(r[1]) << 16);
    outv.y = (unsigned)f2bf(r[2]) | ((unsigned)f2bf(r[3]) << 16);
    outv.z = (unsigned)f2bf(r[4]) | ((unsigned)f2bf(r[5]) << 16);
    outv.w = (unsigned)f2bf(r[6]) | ((unsigned)f2bf(r[7]) << 16);
    // chunk-swizzle by point row: col' = col ^ ((pt&7)*8) (stays in 64-col group)
    *(uint4*)(xT + pt * K1 + ((C1 + c0) ^ (((int)pt & 7) * 8))) = outv;
}

// ================= MFMA GEMM1: h1 = xT @ W1^T (bf16), + BN1 stats ==========
// Plain-__syncthreads 2-phase double buffer: issue DMA for tile k+1 into
// buf^1, compute tile k from buf, ONE __syncthreads (drains the prefetch AND
// protects buffer reuse). Inputs pre-swizzled in global => conflict-free LDS;
// fragment reads XOR chunk by (row&7). Stats via register shfl reduce.
// Grid: (col-blocks fast, row-blocks slow) so A-panel sharers are adjacent.
#define TM 128
#define TN 128
#define TK 64
__launch_bounds__(256)
__global__ void k_gemm1(const unsigned short* __restrict__ xT,
                        const unsigned short* __restrict__ W1b,
                        unsigned short* __restrict__ h1,
                        float* __restrict__ sum1, float* __restrict__ ssq1) {
    __shared__ unsigned short smem[2][TM * TK + TN * TK];   // [buf][ As | Bs ] = 64 KB
    const int t = threadIdx.x;
    const int lane = t & 63, w = t >> 6;
    const int wm = w >> 1, wc = w & 1;
    const long rbase = (long)blockIdx.y * TM;
    const int cb = blockIdx.x * TN;

    v4f acc[4][4];
#pragma unroll
    for (int r = 0; r < 4; ++r)
#pragma unroll
        for (int c = 0; c < 4; ++c) acc[r][c] = (v4f)(0.f);

    const int srow = w * 32 + (lane >> 3);
    const int sch = (lane & 7) * 8;          // LINEAR source col (monotone DMA)
    const unsigned short* Ag = xT + (rbase + srow) * K1 + sch;
    const unsigned short* Bg = W1b + (size_t)(cb + srow) * K1 + sch;

    const int ln = lane & 15, q = lane >> 4;
    const int xs = (ln & 7) * 8;             // read-side XOR: (row&7)*8

    // prologue: tile 0 into buf 0, drain
#pragma unroll
    for (int j = 0; j < 4; ++j) {
        gload16(Ag + (size_t)(j * 8) * K1, smem[0] + (w * 32 + j * 8) * TK);
        gload16(Bg + (size_t)(j * 8) * K1, smem[0] + TM * TK + (w * 32 + j * 8) * TK);
    }
    __syncthreads();

    for (int k0 = 0; k0 < K1; k0 += TK) {
        const int p = (k0 >> 6) & 1;
        if (k0 + TK < K1) {
            // issue next tile's DMA into the other buffer; it flies during compute
#pragma unroll
            for (int j = 0; j < 4; ++j) {
                gload16(Ag + (size_t)(j * 8) * K1 + k0 + TK, smem[p ^ 1] + (w * 32 + j * 8) * TK);
                gload16(Bg + (size_t)(j * 8) * K1 + k0 + TK, smem[p ^ 1] + TM * TK + (w * 32 + j * 8) * TK);
            }
        }
        const unsigned short* ApL = smem[p] + (wm * 64 + ln) * TK;
        const unsigned short* BpL = smem[p] + TM * TK + (wc * 64 + ln) * TK;
#pragma unroll
        for (int ks = 0; ks < 2; ++ks) {
            const int off = (q * 8 + ks * 32) ^ xs;
            v8s af[4], bg[4];
#pragma unroll
            for (int r = 0; r < 4; ++r) af[r] = *(const v8s*)(ApL + r * 16 * TK + off);
#pragma unroll
            for (int c = 0; c < 4; ++c) bg[c] = *(const v8s*)(BpL + c * 16 * TK + off);
#pragma unroll
            for (int r = 0; r < 4; ++r)
#pragma unroll
                for (int c = 0; c < 4; ++c)
                    acc[r][c] = __builtin_amdgcn_mfma_f32_16x16x32_bf16(af[r], bg[c], acc[r][c], 0, 0, 0);
        }
        // drains next-tile DMA (ready for k+1) AND protects buf p from reuse
        __syncthreads();
    }

    // ---- epilogue: reg stats + XOR-swizzled LDS transpose -> coalesced stores
    unsigned short* ep = (unsigned short*)smem;   // 128x128 bf16 tile (32 KB)
#pragma unroll
    for (int c = 0; c < 4; ++c) {
        int col = wc * 64 + c * 16 + ln;            // local col 0..127
        int cc = col >> 3, ci = col & 7;
        float s = 0.f, sq = 0.f;
#pragma unroll
        for (int r = 0; r < 4; ++r)
#pragma unroll
            for (int i = 0; i < 4; ++i) {
                int row = wm * 64 + r * 16 + q * 4 + i;
                float v = acc[r][c][i];
                ep[row * 128 + 8 * (cc ^ (row & 15)) + ci] = f2bf(v);
                s += v; sq += v * v;
            }
        // reduce over q (lane bits 4,5); lanes<16 hold per-col totals
        s += __shfl_xor(s, 16); sq += __shfl_xor(sq, 16);
        s += __shfl_xor(s, 32); sq += __shfl_xor(sq, 32);
        if (lane < 16) {
            atomicAdd(&sum1[cb + col], s);
            atomicAdd(&ssq1[cb + col], sq);
        }
    }
    __syncthreads();
    {
        int rr = t >> 4, cc2 = t & 15;
#pragma unroll
        for (int j = 0; j < 8; ++j) {
            int row = rr + 16 * j;
            uint4 v = *(const uint4*)&ep[row * 128 + 8 * (cc2 ^ (row & 15))];
            *(uint4*)&h1[(size_t)(rbase + row) * CO + cb + cc2 * 8] = v;
        }
    }
}

// ====== MFMA GEMM2: h2 = relu(bn1(h1)) @ W2^T -> [B,CO,N] + BN2 stats =======
// r4-identical schedule (stage->sync->compute->sync; B DMA overlaps the BN1
// conversion VALU). A: reg-load -> BN1+ReLU -> ds_write at chunk-swizzled
// slot. B: W2b pre-swizzled in global, linear DMA. Stats via reg shfl reduce.
__launch_bounds__(256)
__global__ void k_gemm2(const unsigned short* __restrict__ h1,
                        const unsigned short* __restrict__ W2b,
                        const float* __restrict__ sum1, const float* __restrict__ ssq1,
                        const float* __restrict__ g1, const float* __restrict__ b1,
                        unsigned short* __restrict__ h2,
                        float* __restrict__ sum2, float* __restrict__ ssq2) {
    __shared__ unsigned short smem[TM * TK + TN * TK];
    __shared__ float sc1[CO], sh1[CO];
    unsigned short* As = smem;
    unsigned short* Bs = smem + TM * TK;
    const int t = threadIdx.x;
    const int lane = t & 63, w = t >> 6;
    const int wm = w >> 1, wc = w & 1;
    const long rbase = (long)blockIdx.y * TM;
    const int cb = blockIdx.x * TN;

    // fold BN1 finalize: per-block compute of scale/shift (stream-ordered after gemm1)
    {
        const float invn = 1.f / (float)MTOT;
        float m = sum1[t] * invn;
        float v = ssq1[t] * invn - m * m;
        float s = g1[t] * rsqrtf(v + 1e-5f);
        sc1[t] = s;
        sh1[t] = b1[t] - m * s;
    }
    __syncthreads();

    v4f acc[4][4];
#pragma unroll
    for (int r = 0; r < 4; ++r)
#pragma unroll
        for (int c = 0; c < 4; ++c) acc[r][c] = (v4f)(0.f);

    const int srow = w * 32 + (lane >> 3);
    const int sch = (lane & 7) * 8;
    const unsigned short* Ag = h1 + (rbase + srow) * CO + sch;
    const unsigned short* Bg = W2b + (size_t)(cb + srow) * CO + sch;
    // A ds_write at chunk-swizzled slot (matches read-side XOR)
    unsigned short* AsW = As + srow * TK + (sch ^ ((srow & 7) * 8));

    for (int k0 = 0; k0 < CO; k0 += TK) {
#pragma unroll
        for (int j = 0; j < 4; ++j)
            gload16(Bg + (size_t)(j * 8) * CO + k0, Bs + (w * 32 + j * 8) * TK);
        float4 sca = *(const float4*)(sc1 + k0 + sch);
        float4 scb = *(const float4*)(sc1 + k0 + sch + 4);
        float4 sha = *(const float4*)(sh1 + k0 + sch);
        float4 shb = *(const float4*)(sh1 + k0 + sch + 4);
#pragma unroll
        for (int j = 0; j < 4; ++j) {
            uint4 av = *(const uint4*)(Ag + (size_t)(j * 8) * CO + k0);
            float y0 = fmaxf(bf2f((unsigned short)(av.x & 0xffff)) * sca.x + sha.x, 0.f);
            float y1 = fmaxf(bf2f((unsigned short)(av.x >> 16)) * sca.y + sha.y, 0.f);
            float y2 = fmaxf(bf2f((unsigned short)(av.y & 0xffff)) * sca.z + sha.z, 0.f);
            float y3 = fmaxf(bf2f((unsigned short)(av.y >> 16)) * sca.w + sha.w, 0.f);
            float y4 = fmaxf(bf2f((unsigned short)(av.z & 0xffff)) * scb.x + shb.x, 0.f);
            float y5 = fmaxf(bf2f((unsigned short)(av.z >> 16)) * scb.y + shb.y, 0.f);
            float y6 = fmaxf(bf2f((unsigned short)(av.w & 0xffff)) * scb.z + shb.z, 0.f);
            float y7 = fmaxf(bf2f((unsigned short)(av.w >> 16)) * scb.w + shb.w, 0.f);
            uint4 ov;
            ov.x = (unsigned)f2bf(y0) | ((unsigned)f2bf(y1) << 16);
            ov.y = (unsigned)f2bf(y2) | ((unsigned)f2bf(y3) << 16);
            ov.z = (unsigned)f2bf(y4) | ((unsigned)f2bf(y5) << 16);
            ov.w = (unsigned)f2bf(y6) | ((unsigned)f2bf(y7) << 16);
            *(uint4*)(AsW + (j * 8) * TK) = ov;
        }
        __syncthreads();
        const int ln = lane & 15, q = lane >> 4;
        const int xs = (ln & 7) * 8;
        const unsigned short* ApL = As + (wm * 64 + ln) * TK;
        const unsigned short* BpL = Bs + (wc * 64 + ln) * TK;
#pragma unroll
        for (int ks = 0; ks < 2; ++ks) {
            const int off = (q * 8 + ks * 32) ^ xs;
            v8s af[4], bg4[4];
#pragma unroll
            for (int r = 0; r < 4; ++r) af[r] = *(const v8s*)(ApL + r * 16 * TK + off);
#pragma unroll
            for (int c = 0; c < 4; ++c) bg4[c] = *(const v8s*)(BpL + c * 16 * TK + off);
#pragma unroll
            for (int r = 0; r < 4; ++r)
#pragma unroll
                for (int c = 0; c < 4; ++c)
                    acc[r][c] = __builtin_amdgcn_mfma_f32_16x16x32_bf16(af[r], bg4[c], acc[r][c], 0, 0, 0);
        }
        __syncthreads();
    }

    // ---- epilogue: reg stats + transposed swizzled tile -> n-contiguous stores
    const int q = lane >> 4, ln = lane & 15;
    const int b = (int)(rbase >> 14);
    const int nb = (int)(rbase & (NN - 1));
#pragma unroll
    for (int c = 0; c < 4; ++c) {
        int ol = wc * 64 + c * 16 + ln;             // local out-channel 0..127
        float s = 0.f, sq = 0.f;
#pragma unroll
        for (int r = 0; r < 4; ++r)
#pragma unroll
            for (int i = 0; i < 4; ++i) {
                int row = wm * 64 + r * 16 + q * 4 + i;  // local n
                int rc = row >> 3, ri = row & 7;
                float v = acc[r][c][i];
                smem[ol * 128 + 8 * (rc ^ (ol & 15)) + ri] = f2bf(v);
                s += v; sq += v * v;
            }
        s += __shfl_xor(s, 16); sq += __shfl_xor(sq, 16);
        s += __shfl_xor(s, 32); sq += __shfl_xor(sq, 32);
        if (lane < 16) {
            atomicAdd(&sum2[cb + ol], s);
            atomicAdd(&ssq2[cb + ol], sq);
        }
    }
    __syncthreads();
    {
        int oo = t >> 4, nc = t & 15;
#pragma unroll
        for (int j = 0; j < 8; ++j) {
            int ol = oo + 16 * j;
            uint4 v = *(const uint4*)&smem[ol * 128 + 8 * (nc ^ (ol & 15))];
            *(uint4*)&h2[(((size_t)(b * CO + cb + ol)) << 14) + nb + nc * 8] = v;
        }
    }
}

// ---------------- final BN2+ReLU -> fp32 out (BN2 finalize folded) ----------
__global__ void k_apply(const unsigned short* __restrict__ h2,
                        const float* __restrict__ sum2, const float* __restrict__ ssq2,
                        const float* __restrict__ g2, const float* __restrict__ b2,
                        float* __restrict__ out) {
    __shared__ float ss[2];
    int o = (blockIdx.x >> 4) & 255;   // each block spans 1024 elems within one channel
    if (threadIdx.x == 0) {
        const float invn = 1.f / (float)MTOT;
        float m = sum2[o] * invn;
        float v = ssq2[o] * invn - m * m;
        float s = g2[o] * rsqrtf(v + 1e-5f);
        ss[0] = s;
        ss[1] = b2[o] - m * s;
    }
    __syncthreads();
    float s = ss[0], d = ss[1];
    size_t i = ((size_t)blockIdx.x * 256 + threadIdx.x) * 4;
    ushort4 hv = *(const ushort4*)(h2 + i);
    float4 v;
    v.x = fmaxf(bf2f(hv.x) * s + d, 0.f);
    v.y = fmaxf(bf2f(hv.y) * s + d, 0.f);
    v.z = fmaxf(bf2f(hv.z) * s + d, 0.f);
    v.w = fmaxf(bf2f(hv.w) * s + d, 0.f);
    *(float4*)&out[i] = v;
}

extern "C" void kernel_launch(void* const* d_in, const int* in_sizes, int n_in,
                              void* d_out, int out_size, void* d_ws, size_t ws_size,
                              hipStream_t stream) {
    const float* p1 = (const float*)d_in[0];
    const float* p2 = (const float*)d_in[1];
    const float* f1 = (const float*)d_in[2];
    const float* f2 = (const float*)d_in[3];
    const void*  idx = d_in[4];
    const float* W1 = (const float*)d_in[5];
    const float* g1 = (const float*)d_in[6];
    const float* b1 = (const float*)d_in[7];
    const float* W2 = (const float*)d_in[8];
    const float* g2 = (const float*)d_in[9];
    const float* b2 = (const float*)d_in[10];
    float* out = (float*)d_out;

    char* ws = (char*)d_ws;
    float* stats = (float*)(ws + STATS_OFF);
    float* sum1 = stats + 0;     float* ssq1 = stats + 256;
    float* sum2 = stats + 1024;  float* ssq2 = stats + 1280;
    int* flag64 = (int*)(ws + FLAG_OFF);
    unsigned short* W1b = (unsigned short*)(ws + W1B_OFF);
    unsigned short* W2b = (unsigned short*)(ws + W2B_OFF);
    unsigned short* f2t = (unsigned short*)(ws + F2T_OFF);
    unsigned short* xT  = (unsigned short*)(ws + XT_OFF);
    unsigned short* h2  = (unsigned short*)(ws + H2_OFF);

    unsigned short* h1 = (unsigned short*)d_out;  // 67 MB bf16 scratch in d_out

    k_prep<<<577, 256, 0, stream>>>(idx, flag64, stats, W1, W1b, W2, W2b);
    k_tr_f2<<<dim3(MM / 32, C2 / 64, BB), 256, 0, stream>>>(f2, f2t);
    k_tr_f1<<<dim3(NN / 32, 1, BB), 256, 0, stream>>>(f1, xT);
    k_interp<<<MTOT / 8, 256, 0, stream>>>(p1, p2, idx, flag64, f2t, xT);
    k_gemm1<<<dim3(CO / TN, MTOT / TM), 256, 0, stream>>>(xT, W1b, h1, sum1, ssq1);
    k_gemm2<<<dim3(CO / TN, MTOT / TM), 256, 0, stream>>>(h1, W2b, sum1, ssq1, g1, b1, h2, sum2, ssq2);
    k_apply<<<(int)((size_t)out_size / 4 / 256), 256, 0, stream>>>(h2, sum2, ssq2, g2, b2, out);
}

// Round 7
// 404.498 us; speedup vs baseline: 1.8193x; 1.0031x over previous
//
#include <hip/hip_runtime.h>
#include <hip/hip_bf16.h>

// Problem constants
#define BB 8
#define NN 16384
#define MM 4096
#define C1 64
#define C2 256
#define K1 320            // C1 + C2
#define CO 256
#define MTOT (BB * NN)    // 131072

// Workspace layout (bytes)
#define STATS_OFF 0                 // 8*256 floats
#define FLAG_OFF  8192
#define W1B_OFF   16384             // bf16 256x320
#define W2B_OFF   180224            // bf16 256x256
#define F2T_OFF   327680            // bf16 [B,M,C2] = 16777216 B
#define XT_OFF    (327680 + 16777216)              // bf16 [MTOT,320]
#define H2_OFF    (327680 + 16777216 + 83886080)   // bf16 [B,CO,N]

// Global column-chunk swizzle: within each 64-col (8-chunk) group, the 16B
// chunk c of row r is stored at chunk c ^ (r&7). Linear-source global_load_lds
// (monotone lane addresses - swizzled-source DMA was the r1/r2 4x poison)
// lands a bank-conflict-free layout in LDS; fragment reads XOR back.
// r6: gemm1 plain-__syncthreads 2-phase double buffer (-17us, verified).
// r7: same 2-phase pipeline applied to gemm2 (B-DMA || BN-convert || A-loads
// || MFMA per phase, one barrier/iter). Counted-vmcnt stays BANNED (r5 raced).

typedef short v8s __attribute__((ext_vector_type(8)));
typedef float v4f __attribute__((ext_vector_type(4)));

__device__ __forceinline__ float bf2f(unsigned short u) {
    unsigned v = ((unsigned)u) << 16;
    float f;
    __builtin_memcpy(&f, &v, 4);
    return f;
}
__device__ __forceinline__ unsigned short f2bf(float f) {
    unsigned u;
    __builtin_memcpy(&u, &f, 4);
    unsigned r = u + 0x7fffu + ((u >> 16) & 1u);  // RNE
    return (unsigned short)(r >> 16);
}
__device__ __forceinline__ void gload16(const unsigned short* g, unsigned short* l) {
    __builtin_amdgcn_global_load_lds((const __attribute__((address_space(1))) unsigned int*)g,
                                     (__attribute__((address_space(3))) unsigned int*)l, 16, 0, 0);
}

// ---------------- prep: zero stats, idx width flag, W1/W2 -> bf16 ----------
// Weights stored column-chunk-swizzled: col' = col ^ ((row&7)<<3).
__global__ void k_prep(const void* idx_raw, int* flag64, float* stats,
                       const float* __restrict__ W1, unsigned short* __restrict__ W1b,
                       const float* __restrict__ W2, unsigned short* __restrict__ W2b) {
    int blk = blockIdx.x;
    int t = threadIdx.x;
    if (blk < 320) {
        int e = blk * 256 + t;
        int row = e / K1, col = e - row * K1;
        W1b[row * K1 + (col ^ ((row & 7) << 3))] = f2bf(W1[e]);
    } else if (blk < 576) {
        int e = (blk - 320) * 256 + t;
        int row = e >> 8, col = e & 255;
        W2b[row * CO + (col ^ ((row & 7) << 3))] = f2bf(W2[e]);
    } else {
        for (int i = t; i < 8 * 256; i += 256) stats[i] = 0.f;
        if (t == 0) {
            const int* a = (const int*)idx_raw;
            int all0 = 1;
            for (int j = 1; j < 64; j += 2) all0 &= (a[j] == 0);
            *flag64 = all0;  // 1 => idx int64
        }
    }
}

// ------- transpose f2 [B,C2,M] -> f2t bf16 [B,M,C2]; 64ch x 32m tiles ------
__global__ void k_tr_f2(const float* __restrict__ f2, unsigned short* __restrict__ f2t) {
    __shared__ float tile[64][33];
    int b = blockIdx.z;
    int c0 = blockIdx.y * 64;
    int m0 = blockIdx.x * 32;
    int t = threadIdx.x;
    int lm = t & 31, lc = t >> 5;          // lc 0..7
    const float* src = f2 + ((size_t)b * C2 + c0) * MM + m0;
#pragma unroll
    for (int j = 0; j < 8; ++j)
        tile[lc + 8 * j][lm] = src[(size_t)(lc + 8 * j) * MM + lm];
    __syncthreads();
    int m = t >> 3, c8 = (t & 7) * 8;      // m 0..31, c8 0..56
    unsigned short tmp[8];
#pragma unroll
    for (int k = 0; k < 8; ++k) tmp[k] = f2bf(tile[c8 + k][m]);
    uint4 v;
    v.x = (unsigned)tmp[0] | ((unsigned)tmp[1] << 16);
    v.y = (unsigned)tmp[2] | ((unsigned)tmp[3] << 16);
    v.z = (unsigned)tmp[4] | ((unsigned)tmp[5] << 16);
    v.w = (unsigned)tmp[6] | ((unsigned)tmp[7] << 16);
    *(uint4*)&f2t[((size_t)b * MM + m0 + m) * C2 + c0 + c8] = v;
}

// ------- transpose f1 [B,C1,N] -> xT[:,0:64] bf16; 64ch x 32n tiles --------
// xT stored chunk-swizzled by row: chunk' = chunk ^ (n&7) within the group.
__global__ void k_tr_f1(const float* __restrict__ f1, unsigned short* __restrict__ xT) {
    __shared__ float tile[64][33];
    int b = blockIdx.z;
    int n0 = blockIdx.x * 32;
    int t = threadIdx.x;
    int lm = t & 31, lc = t >> 5;
    const float* src = f1 + ((size_t)b * C1) * NN + n0;
#pragma unroll
    for (int j = 0; j < 8; ++j)
        tile[lc + 8 * j][lm] = src[(size_t)(lc + 8 * j) * NN + lm];
    __syncthreads();
    int m = t >> 3, c8 = (t & 7) * 8;
    unsigned short tmp[8];
#pragma unroll
    for (int k = 0; k < 8; ++k) tmp[k] = f2bf(tile[c8 + k][m]);
    uint4 v;
    v.x = (unsigned)tmp[0] | ((unsigned)tmp[1] << 16);
    v.y = (unsigned)tmp[2] | ((unsigned)tmp[3] << 16);
    v.z = (unsigned)tmp[4] | ((unsigned)tmp[5] << 16);
    v.w = (unsigned)tmp[6] | ((unsigned)tmp[7] << 16);
    // row = n0+m; (row&7) == (m&7) since n0 % 32 == 0
    *(uint4*)&xT[((size_t)b * NN + n0 + m) * K1 + (c8 ^ ((m & 7) * 8))] = v;
}

// ---------------- 3-NN inverse-distance interpolation -> xT[:,64:320] -------
__global__ void k_interp(const float* __restrict__ p1, const float* __restrict__ p2,
                         const void* __restrict__ idxv, const int* __restrict__ flag64,
                         const unsigned short* __restrict__ f2t,
                         unsigned short* __restrict__ xT) {
    int t = threadIdx.x;
    int p = t >> 5, lane = t & 31;
    size_t pt = (size_t)blockIdx.x * 8 + p;
    int b = (int)(pt >> 14);
    int m0, m1, m2;
    if (*flag64) {
        const long long* id = (const long long*)idxv;
        m0 = (int)id[pt * 3 + 0]; m1 = (int)id[pt * 3 + 1]; m2 = (int)id[pt * 3 + 2];
    } else {
        const int* id = (const int*)idxv;
        m0 = id[pt * 3 + 0]; m1 = id[pt * 3 + 1]; m2 = id[pt * 3 + 2];
    }
    float qx = p1[pt * 3 + 0], qy = p1[pt * 3 + 1], qz = p1[pt * 3 + 2];
    const float* pb = p2 + (size_t)b * MM * 3;
    float dx, dy, dz;
    dx = qx - pb[m0 * 3 + 0]; dy = qy - pb[m0 * 3 + 1]; dz = qz - pb[m0 * 3 + 2];
    float d0 = dx * dx + dy * dy + dz * dz;
    dx = qx - pb[m1 * 3 + 0]; dy = qy - pb[m1 * 3 + 1]; dz = qz - pb[m1 * 3 + 2];
    float d1 = dx * dx + dy * dy + dz * dz;
    dx = qx - pb[m2 * 3 + 0]; dy = qy - pb[m2 * 3 + 1]; dz = qz - pb[m2 * 3 + 2];
    float d2v = dx * dx + dy * dy + dz * dz;
    float r0 = 1.f / (d0 + 1e-8f), r1 = 1.f / (d1 + 1e-8f), r2 = 1.f / (d2v + 1e-8f);
    float inv = 1.f / (r0 + r1 + r2);
    float w0 = r0 * inv, w1 = r1 * inv, w2 = r2 * inv;

    const unsigned short* fb = f2t + (size_t)b * MM * C2;
    int c0 = lane * 8;
    uint4 va = *(const uint4*)(fb + (size_t)m0 * C2 + c0);
    uint4 vb = *(const uint4*)(fb + (size_t)m1 * C2 + c0);
    uint4 vc = *(const uint4*)(fb + (size_t)m2 * C2 + c0);

    float r[8];
    {
        const unsigned av[4] = {va.x, va.y, va.z, va.w};
        const unsigned bv[4] = {vb.x, vb.y, vb.z, vb.w};
        const unsigned cv[4] = {vc.x, vc.y, vc.z, vc.w};
#pragma unroll
        for (int q = 0; q < 4; ++q) {
            r[2 * q + 0] = w0 * bf2f((unsigned short)(av[q] & 0xffff))
                         + w1 * bf2f((unsigned short)(bv[q] & 0xffff))
                         + w2 * bf2f((unsigned short)(cv[q] & 0xffff));
            r[2 * q + 1] = w0 * bf2f((unsigned short)(av[q] >> 16))
                         + w1 * bf2f((unsigned short)(bv[q] >> 16))
                         + w2 * bf2f((unsigned short)(cv[q] >> 16));
        }
    }
    uint4 outv;
    outv.x = (unsigned)f2bf(r[0]) | ((unsigned)f2bf(r[1]) << 16);
    outv.y = (unsigned)f2bf(r[2]) | ((unsigned)f2bf(r[3]) << 16);
    outv.z = (unsigned)f2bf(r[4]) | ((unsigned)f2bf(r[5]) << 16);
    outv.w = (unsigned)f2bf(r[6]) | ((unsigned)f2bf(r[7]) << 16);
    // chunk-swizzle by point row: col' = col ^ ((pt&7)*8) (stays in 64-col group)
    *(uint4*)(xT + pt * K1 + ((C1 + c0) ^ (((int)pt & 7) * 8))) = outv;
}

// ================= MFMA GEMM1: h1 = xT @ W1^T (bf16), + BN1 stats ==========
// Plain-__syncthreads 2-phase double buffer (r6-verified).
#define TM 128
#define TN 128
#define TK 64
__launch_bounds__(256)
__global__ void k_gemm1(const unsigned short* __restrict__ xT,
                        const unsigned short* __restrict__ W1b,
                        unsigned short* __restrict__ h1,
                        float* __restrict__ sum1, float* __restrict__ ssq1) {
    __shared__ unsigned short smem[2][TM * TK + TN * TK];   // [buf][ As | Bs ] = 64 KB
    const int t = threadIdx.x;
    const int lane = t & 63, w = t >> 6;
    const int wm = w >> 1, wc = w & 1;
    const long rbase = (long)blockIdx.y * TM;
    const int cb = blockIdx.x * TN;

    v4f acc[4][4];
#pragma unroll
    for (int r = 0; r < 4; ++r)
#pragma unroll
        for (int c = 0; c < 4; ++c) acc[r][c] = (v4f)(0.f);

    const int srow = w * 32 + (lane >> 3);
    const int sch = (lane & 7) * 8;          // LINEAR source col (monotone DMA)
    const unsigned short* Ag = xT + (rbase + srow) * K1 + sch;
    const unsigned short* Bg = W1b + (size_t)(cb + srow) * K1 + sch;

    const int ln = lane & 15, q = lane >> 4;
    const int xs = (ln & 7) * 8;             // read-side XOR: (row&7)*8

    // prologue: tile 0 into buf 0, drain
#pragma unroll
    for (int j = 0; j < 4; ++j) {
        gload16(Ag + (size_t)(j * 8) * K1, smem[0] + (w * 32 + j * 8) * TK);
        gload16(Bg + (size_t)(j * 8) * K1, smem[0] + TM * TK + (w * 32 + j * 8) * TK);
    }
    __syncthreads();

    for (int k0 = 0; k0 < K1; k0 += TK) {
        const int p = (k0 >> 6) & 1;
        if (k0 + TK < K1) {
            // issue next tile's DMA into the other buffer; it flies during compute
#pragma unroll
            for (int j = 0; j < 4; ++j) {
                gload16(Ag + (size_t)(j * 8) * K1 + k0 + TK, smem[p ^ 1] + (w * 32 + j * 8) * TK);
                gload16(Bg + (size_t)(j * 8) * K1 + k0 + TK, smem[p ^ 1] + TM * TK + (w * 32 + j * 8) * TK);
            }
        }
        const unsigned short* ApL = smem[p] + (wm * 64 + ln) * TK;
        const unsigned short* BpL = smem[p] + TM * TK + (wc * 64 + ln) * TK;
#pragma unroll
        for (int ks = 0; ks < 2; ++ks) {
            const int off = (q * 8 + ks * 32) ^ xs;
            v8s af[4], bg[4];
#pragma unroll
            for (int r = 0; r < 4; ++r) af[r] = *(const v8s*)(ApL + r * 16 * TK + off);
#pragma unroll
            for (int c = 0; c < 4; ++c) bg[c] = *(const v8s*)(BpL + c * 16 * TK + off);
#pragma unroll
            for (int r = 0; r < 4; ++r)
#pragma unroll
                for (int c = 0; c < 4; ++c)
                    acc[r][c] = __builtin_amdgcn_mfma_f32_16x16x32_bf16(af[r], bg[c], acc[r][c], 0, 0, 0);
        }
        // drains next-tile DMA (ready for k+1) AND protects buf p from reuse
        __syncthreads();
    }

    // ---- epilogue: reg stats + XOR-swizzled LDS transpose -> coalesced stores
    unsigned short* ep = (unsigned short*)smem;   // 128x128 bf16 tile (32 KB)
#pragma unroll
    for (int c = 0; c < 4; ++c) {
        int col = wc * 64 + c * 16 + ln;            // local col 0..127
        int cc = col >> 3, ci = col & 7;
        float s = 0.f, sq = 0.f;
#pragma unroll
        for (int r = 0; r < 4; ++r)
#pragma unroll
            for (int i = 0; i < 4; ++i) {
                int row = wm * 64 + r * 16 + q * 4 + i;
                float v = acc[r][c][i];
                ep[row * 128 + 8 * (cc ^ (row & 15)) + ci] = f2bf(v);
                s += v; sq += v * v;
            }
        // reduce over q (lane bits 4,5); lanes<16 hold per-col totals
        s += __shfl_xor(s, 16); sq += __shfl_xor(sq, 16);
        s += __shfl_xor(s, 32); sq += __shfl_xor(sq, 32);
        if (lane < 16) {
            atomicAdd(&sum1[cb + col], s);
            atomicAdd(&ssq1[cb + col], sq);
        }
    }
    __syncthreads();
    {
        int rr = t >> 4, cc2 = t & 15;
#pragma unroll
        for (int j = 0; j < 8; ++j) {
            int row = rr + 16 * j;
            uint4 v = *(const uint4*)&ep[row * 128 + 8 * (cc2 ^ (row & 15))];
            *(uint4*)&h1[(size_t)(rbase + row) * CO + cb + cc2 * 8] = v;
        }
    }
}

// ====== MFMA GEMM2: h2 = relu(bn1(h1)) @ W2^T -> [B,CO,N] + BN2 stats =======
// r7: 2-phase double buffer, fully unrolled (4 K-tiles, static indices).
// Per iter k: issue B(k+1) DMA -> Bs[p^1]; convert A(k+1) regs (BN1+ReLU) ->
// ds_write As[p^1] (safe: p^1 last read before previous barrier); reload A
// regs with tile k+2 (latency hides under MFMA); compute smem[p]; ONE sync.
__launch_bounds__(256)
__global__ void k_gemm2(const unsigned short* __restrict__ h1,
                        const unsigned short* __restrict__ W2b,
                        const float* __restrict__ sum1, const float* __restrict__ ssq1,
                        const float* __restrict__ g1, const float* __restrict__ b1,
                        unsigned short* __restrict__ h2,
                        float* __restrict__ sum2, float* __restrict__ ssq2) {
    __shared__ unsigned short smem[2][TM * TK + TN * TK];   // 64 KB
    __shared__ float sc1[CO], sh1[CO];
    const int t = threadIdx.x;
    const int lane = t & 63, w = t >> 6;
    const int wm = w >> 1, wc = w & 1;
    const long rbase = (long)blockIdx.y * TM;
    const int cb = blockIdx.x * TN;

    // fold BN1 finalize: per-block compute of scale/shift (stream-ordered after gemm1)
    {
        const float invn = 1.f / (float)MTOT;
        float m = sum1[t] * invn;
        float v = ssq1[t] * invn - m * m;
        float s = g1[t] * rsqrtf(v + 1e-5f);
        sc1[t] = s;
        sh1[t] = b1[t] - m * s;
    }
    __syncthreads();

    v4f acc[4][4];
#pragma unroll
    for (int r = 0; r < 4; ++r)
#pragma unroll
        for (int c = 0; c < 4; ++c) acc[r][c] = (v4f)(0.f);

    const int srow = w * 32 + (lane >> 3);
    const int sch = (lane & 7) * 8;
    const unsigned short* Ag = h1 + (rbase + srow) * CO + sch;
    const unsigned short* Bg = W2b + (size_t)(cb + srow) * CO + sch;
    const int awz = srow * TK + (sch ^ ((srow & 7) * 8));   // A ds_write slot

    const int ln = lane & 15, q = lane >> 4;
    const int xs = (ln & 7) * 8;

    // BN1+ReLU convert of one A reg-tile -> swizzled ds_write into `base`
#define CONV_STORE(AV, KOFF, BASE)                                                     \
    do {                                                                               \
        float4 sca = *(const float4*)(sc1 + (KOFF) + sch);                             \
        float4 scb = *(const float4*)(sc1 + (KOFF) + sch + 4);                         \
        float4 sha = *(const float4*)(sh1 + (KOFF) + sch);                             \
        float4 shb = *(const float4*)(sh1 + (KOFF) + sch + 4);                         \
        _Pragma("unroll")                                                              \
        for (int j = 0; j < 4; ++j) {                                                  \
            uint4 av = (AV)[j];                                                        \
            float y0 = fmaxf(bf2f((unsigned short)(av.x & 0xffff)) * sca.x + sha.x, 0.f); \
            float y1 = fmaxf(bf2f((unsigned short)(av.x >> 16)) * sca.y + sha.y, 0.f); \
            float y2 = fmaxf(bf2f((unsigned short)(av.y & 0xffff)) * sca.z + sha.z, 0.f); \
            float y3 = fmaxf(bf2f((unsigned short)(av.y >> 16)) * sca.w + sha.w, 0.f); \
            float y4 = fmaxf(bf2f((unsigned short)(av.z & 0xffff)) * scb.x + shb.x, 0.f); \
            float y5 = fmaxf(bf2f((unsigned short)(av.z >> 16)) * scb.y + shb.y, 0.f); \
            float y6 = fmaxf(bf2f((unsigned short)(av.w & 0xffff)) * scb.z + shb.z, 0.f); \
            float y7 = fmaxf(bf2f((unsigned short)(av.w >> 16)) * scb.w + shb.w, 0.f); \
            uint4 ov;                                                                  \
            ov.x = (unsigned)f2bf(y0) | ((unsigned)f2bf(y1) << 16);                    \
            ov.y = (unsigned)f2bf(y2) | ((unsigned)f2bf(y3) << 16);                    \
            ov.z = (unsigned)f2bf(y4) | ((unsigned)f2bf(y5) << 16);                    \
            ov.w = (unsigned)f2bf(y6) | ((unsigned)f2bf(y7) << 16);                    \
            *(uint4*)((BASE) + awz + (j * 8) * TK) = ov;                               \
        }                                                                              \
    } while (0)

    // prologue: B(0) DMA -> Bs[0]; A(0),A(1) regs; convert A(0) -> As[0]; sync
    uint4 avc[4], avn[4];
#pragma unroll
    for (int j = 0; j < 4; ++j)
        gload16(Bg + (size_t)(j * 8) * CO, smem[0] + TM * TK + (w * 32 + j * 8) * TK);
#pragma unroll
    for (int j = 0; j < 4; ++j) avc[j] = *(const uint4*)(Ag + (size_t)(j * 8) * CO);
#pragma unroll
    for (int j = 0; j < 4; ++j) avn[j] = *(const uint4*)(Ag + (size_t)(j * 8) * CO + TK);
    CONV_STORE(avc, 0, smem[0]);
    __syncthreads();

#pragma unroll
    for (int kk = 0; kk < 4; ++kk) {
        const int p = kk & 1;
        if (kk < 3) {
            // issue B(k+1) DMA early (flies during convert + MFMA)
#pragma unroll
            for (int j = 0; j < 4; ++j)
                gload16(Bg + (size_t)(j * 8) * CO + (kk + 1) * TK,
                        smem[p ^ 1] + TM * TK + (w * 32 + j * 8) * TK);
            // convert A(k+1) -> As[p^1] (reads avn, then avn is dead)
            CONV_STORE(avn, (kk + 1) * TK, smem[p ^ 1]);
        }
        if (kk < 2) {
            // reload avn with A(k+2); latency hides under the MFMA phase below
#pragma unroll
            for (int j = 0; j < 4; ++j)
                avn[j] = *(const uint4*)(Ag + (size_t)(j * 8) * CO + (kk + 2) * TK);
        }
        const unsigned short* ApL = smem[p] + (wm * 64 + ln) * TK;
        const unsigned short* BpL = smem[p] + TM * TK + (wc * 64 + ln) * TK;
#pragma unroll
        for (int ks = 0; ks < 2; ++ks) {
            const int off = (q * 8 + ks * 32) ^ xs;
            v8s af[4], bg4[4];
#pragma unroll
            for (int r = 0; r < 4; ++r) af[r] = *(const v8s*)(ApL + r * 16 * TK + off);
#pragma unroll
            for (int c = 0; c < 4; ++c) bg4[c] = *(const v8s*)(BpL + c * 16 * TK + off);
#pragma unroll
            for (int r = 0; r < 4; ++r)
#pragma unroll
                for (int c = 0; c < 4; ++c)
                    acc[r][c] = __builtin_amdgcn_mfma_f32_16x16x32_bf16(af[r], bg4[c], acc[r][c], 0, 0, 0);
        }
        // drains B(k+1) DMA, publishes As[p^1] writes, protects smem[p] reuse
        __syncthreads();
    }
#undef CONV_STORE

    // ---- epilogue: reg stats + transposed swizzled tile -> n-contiguous stores
    unsigned short* ep = (unsigned short*)smem;
    const int b = (int)(rbase >> 14);
    const int nb = (int)(rbase & (NN - 1));
#pragma unroll
    for (int c = 0; c < 4; ++c) {
        int ol = wc * 64 + c * 16 + ln;             // local out-channel 0..127
        float s = 0.f, sq = 0.f;
#pragma unroll
        for (int r = 0; r < 4; ++r)
#pragma unroll
            for (int i = 0; i < 4; ++i) {
                int row = wm * 64 + r * 16 + q * 4 + i;  // local n
                int rc = row >> 3, ri = row & 7;
                float v = acc[r][c][i];
                ep[ol * 128 + 8 * (rc ^ (ol & 15)) + ri] = f2bf(v);
                s += v; sq += v * v;
            }
        s += __shfl_xor(s, 16); sq += __shfl_xor(sq, 16);
        s += __shfl_xor(s, 32); sq += __shfl_xor(sq, 32);
        if (lane < 16) {
            atomicAdd(&sum2[cb + ol], s);
            atomicAdd(&ssq2[cb + ol], sq);
        }
    }
    __syncthreads();
    {
        int oo = t >> 4, nc = t & 15;
#pragma unroll
        for (int j = 0; j < 8; ++j) {
            int ol = oo + 16 * j;
            uint4 v = *(const uint4*)&ep[ol * 128 + 8 * (nc ^ (ol & 15))];
            *(uint4*)&h2[(((size_t)(b * CO + cb + ol)) << 14) + nb + nc * 8] = v;
        }
    }
}

// ---------------- final BN2+ReLU -> fp32 out (BN2 finalize folded) ----------
__global__ void k_apply(const unsigned short* __restrict__ h2,
                        const float* __restrict__ sum2, const float* __restrict__ ssq2,
                        const float* __restrict__ g2, const float* __restrict__ b2,
                        float* __restrict__ out) {
    __shared__ float ss[2];
    int o = (blockIdx.x >> 4) & 255;   // each block spans 1024 elems within one channel
    if (threadIdx.x == 0) {
        const float invn = 1.f / (float)MTOT;
        float m = sum2[o] * invn;
        float v = ssq2[o] * invn - m * m;
        float s = g2[o] * rsqrtf(v + 1e-5f);
        ss[0] = s;
        ss[1] = b2[o] - m * s;
    }
    __syncthreads();
    float s = ss[0], d = ss[1];
    size_t i = ((size_t)blockIdx.x * 256 + threadIdx.x) * 4;
    ushort4 hv = *(const ushort4*)(h2 + i);
    float4 v;
    v.x = fmaxf(bf2f(hv.x) * s + d, 0.f);
    v.y = fmaxf(bf2f(hv.y) * s + d, 0.f);
    v.z = fmaxf(bf2f(hv.z) * s + d, 0.f);
    v.w = fmaxf(bf2f(hv.w) * s + d, 0.f);
    *(float4*)&out[i] = v;
}

extern "C" void kernel_launch(void* const* d_in, const int* in_sizes, int n_in,
                              void* d_out, int out_size, void* d_ws, size_t ws_size,
                              hipStream_t stream) {
    const float* p1 = (const float*)d_in[0];
    const float* p2 = (const float*)d_in[1];
    const float* f1 = (const float*)d_in[2];
    const float* f2 = (const float*)d_in[3];
    const void*  idx = d_in[4];
    const float* W1 = (const float*)d_in[5];
    const float* g1 = (const float*)d_in[6];
    const float* b1 = (const float*)d_in[7];
    const float* W2 = (const float*)d_in[8];
    const float* g2 = (const float*)d_in[9];
    const float* b2 = (const float*)d_in[10];
    float* out = (float*)d_out;

    char* ws = (char*)d_ws;
    float* stats = (float*)(ws + STATS_OFF);
    float* sum1 = stats + 0;     float* ssq1 = stats + 256;
    float* sum2 = stats + 1024;  float* ssq2 = stats + 1280;
    int* flag64 = (int*)(ws + FLAG_OFF);
    unsigned short* W1b = (unsigned short*)(ws + W1B_OFF);
    unsigned short* W2b = (unsigned short*)(ws + W2B_OFF);
    unsigned short* f2t = (unsigned short*)(ws + F2T_OFF);
    unsigned short* xT  = (unsigned short*)(ws + XT_OFF);
    unsigned short* h2  = (unsigned short*)(ws + H2_OFF);

    unsigned short* h1 = (unsigned short*)d_out;  // 67 MB bf16 scratch in d_out

    k_prep<<<577, 256, 0, stream>>>(idx, flag64, stats, W1, W1b, W2, W2b);
    k_tr_f2<<<dim3(MM / 32, C2 / 64, BB), 256, 0, stream>>>(f2, f2t);
    k_tr_f1<<<dim3(NN / 32, 1, BB), 256, 0, stream>>>(f1, xT);
    k_interp<<<MTOT / 8, 256, 0, stream>>>(p1, p2, idx, flag64, f2t, xT);
    k_gemm1<<<dim3(CO / TN, MTOT / TM), 256, 0, stream>>>(xT, W1b, h1, sum1, ssq1);
    k_gemm2<<<dim3(CO / TN, MTOT / TM), 256, 0, stream>>>(h1, W2b, sum1, ssq1, g1, b1, h2, sum2, ssq2);
    k_apply<<<(int)((size_t)out_size / 4 / 256), 256, 0, stream>>>(h2, sum2, ssq2, g2, b2, out);
}